// Round 5
// baseline (304.001 us; speedup 1.0000x reference)
//
#include <hip/hip_runtime.h>
#include <math.h>

typedef __attribute__((ext_vector_type(8))) short short8;
typedef __attribute__((ext_vector_type(4))) float floatx4;

__device__ __forceinline__ ushort f2b(float f) {
  unsigned u = __float_as_uint(f);
  unsigned r = u + 0x7FFFu + ((u >> 16) & 1u);
  return (ushort)(r >> 16);
}

// ====== mega prep: convert obs/h0/Wih/Whh + transpose Wobs/W1/W2 + misc ======
__global__ __launch_bounds__(256) void prep_kernel(
    const float* __restrict__ obs, ushort* __restrict__ obs_bf,
    const float* __restrict__ h0, ushort* __restrict__ h0_bf,
    const float* __restrict__ Wih, ushort* __restrict__ Wih_bf,
    const float* __restrict__ Whh, ushort* __restrict__ Whh_bf,
    const float* __restrict__ Wobs, ushort* __restrict__ WobsT,
    const float* __restrict__ W1, ushort* __restrict__ W1T,
    const float* __restrict__ W2, ushort* __restrict__ W2T,
    const float* __restrict__ Wa, const float* __restrict__ Wv,
    const float* __restrict__ ba, const float* __restrict__ bv,
    const float* __restrict__ bih, const float* __restrict__ bhh,
    ushort* __restrict__ WaTe, float* __restrict__ bias_ext, float* __restrict__ bias12)
{
  __shared__ float tile[32][33];
  const int bid = blockIdx.x;
  const int tid = threadIdx.x;
  if (bid < 1024) {
    // flat bf16 conversion: obs(1048576) h0(1048576) Wih(262144) Whh(262144)
    const int q0 = 262144, q1 = 262144, q2 = 65536, q3 = 65536;
    const int tot = q0 + q1 + q2 + q3;
    for (int idx = bid * 256 + tid; idx < tot; idx += 1024 * 256) {
      const float* s; ushort* d; int i = idx;
      if (i < q0) { s = obs; d = obs_bf; }
      else if ((i -= q0) < q1) { s = h0; d = h0_bf; }
      else if ((i -= q1) < q2) { s = Wih; d = Wih_bf; }
      else { i -= q2; s = Whh; d = Whh_bf; }
      const float4 v = *(const float4*)(s + (size_t)i * 4);
      ushort4 o; o.x = f2b(v.x); o.y = f2b(v.y); o.z = f2b(v.z); o.w = f2b(v.w);
      *(ushort4*)(d + (size_t)i * 4) = o;
    }
  } else if (bid < 1216) {
    // transpose fp32 [256][256] -> bf16 [256][256]
    const int t = bid - 1024;
    const int mat = t >> 6, sub = t & 63;
    const float* in = mat == 0 ? Wobs : (mat == 1 ? W1 : W2);
    ushort* outp = mat == 0 ? WobsT : (mat == 1 ? W1T : W2T);
    const int c0 = (sub & 7) * 32, r0 = (sub >> 3) * 32;
    const int tx = tid & 31, ty = tid >> 5;
    #pragma unroll
    for (int p = 0; p < 32; p += 8)
      tile[ty + p][tx] = in[(size_t)(r0 + ty + p) * 256 + c0 + tx];
    __syncthreads();
    #pragma unroll
    for (int p = 0; p < 32; p += 8)
      outp[(size_t)(c0 + ty + p) * 256 + r0 + tx] = f2b(tile[tx][ty + p]);
  } else {
    const int idx = (bid - 1216) * 256 + tid;
    if (idx < 65536) {
      const int n = idx >> 9, k = idx & 511;
      const float v = n < 64 ? Wa[(size_t)k * 64 + n] : (n == 64 ? Wv[k] : 0.0f);
      WaTe[idx] = f2b(v);
    } else if (idx < 65536 + 128) {
      const int n = idx - 65536;
      bias_ext[n] = n < 64 ? ba[n] : (n == 64 ? bv[0] : 0.0f);
    } else if (idx < 65536 + 128 + 1024) {
      const int n = idx - 65536 - 128;
      bias12[n] = bih[n] + bhh[n];
    }
  }
}

// ===== MFMA GEMM: C[M,N] = A1@B1^T + A2@B2^T + bias (all NT, bf16 in) =====
template<int BM, int BN, bool OUT_BF16>
__global__ __launch_bounds__(256) void mfma_gemm(
    const ushort* __restrict__ A1, int lda1,
    const ushort* __restrict__ B1, int ldb1, int K1,
    const ushort* __restrict__ A2, int lda2,
    const ushort* __restrict__ B2, int ldb2, int K2,
    const float* __restrict__ bias,
    void* __restrict__ Cv, int N)
{
  constexpr int LDT = 40;   // 32 + 8 pad (shorts) -> 2-way bank alias (free)
  __shared__ __align__(16) ushort As[BM * LDT];
  __shared__ __align__(16) ushort Bs[BN * LDT];
  const int tid = threadIdx.x;
  const int wave = tid >> 6, lane = tid & 63;
  const int wr = wave >> 1, wc = wave & 1;
  const int m0 = blockIdx.y * BM, n0 = blockIdx.x * BN;
  constexpr int MI = BM / 32;
  constexpr int NI = BN / 32;
  floatx4 acc[MI][NI] = {};
  const int r = tid >> 2, kq = tid & 3;
  const int lm = lane & 15, lq = lane >> 4;
  const int Ktot = K1 + K2;
  for (int k0 = 0; k0 < Ktot; k0 += 32) {
    const ushort* A; const ushort* B; int lda, ldb, kk;
    if (k0 < K1) { A = A1; B = B1; lda = lda1; ldb = ldb1; kk = k0; }
    else         { A = A2; B = B2; lda = lda2; ldb = ldb2; kk = k0 - K1; }
    #pragma unroll
    for (int p = 0; p < BM / 64; ++p) {
      const int rr = r + p * 64;
      *(float4*)&As[rr * LDT + kq * 8] =
          *(const float4*)&A[(size_t)(m0 + rr) * lda + kk + kq * 8];
    }
    #pragma unroll
    for (int p = 0; p < BN / 64; ++p) {
      const int rr = r + p * 64;
      *(float4*)&Bs[rr * LDT + kq * 8] =
          *(const float4*)&B[(size_t)(n0 + rr) * ldb + kk + kq * 8];
    }
    __syncthreads();
    short8 af[MI], bfr[NI];
    #pragma unroll
    for (int i = 0; i < MI; ++i)
      af[i] = *(const short8*)&As[(wr * (BM / 2) + i * 16 + lm) * LDT + lq * 8];
    #pragma unroll
    for (int j = 0; j < NI; ++j)
      bfr[j] = *(const short8*)&Bs[(wc * (BN / 2) + j * 16 + lm) * LDT + lq * 8];
    #pragma unroll
    for (int i = 0; i < MI; ++i)
      #pragma unroll
      for (int j = 0; j < NI; ++j)
        acc[i][j] = __builtin_amdgcn_mfma_f32_16x16x32_bf16(af[i], bfr[j], acc[i][j], 0, 0, 0);
    __syncthreads();
  }
  #pragma unroll
  for (int i = 0; i < MI; ++i) {
    #pragma unroll
    for (int j = 0; j < NI; ++j) {
      const int col = n0 + wc * (BN / 2) + j * 16 + lm;
      const float badd = bias ? bias[col] : 0.0f;
      #pragma unroll
      for (int t = 0; t < 4; ++t) {
        const int row = m0 + wr * (BM / 2) + i * 16 + lq * 4 + t;
        const float v = acc[i][j][t] + badd;
        if (OUT_BF16) ((ushort*)Cv)[(size_t)row * N + col] = f2b(v);
        else          ((float*)Cv)[(size_t)row * N + col] = v;
      }
    }
  }
}

// ====== LSTM cell + fused per-block min/max partials + bf16 h copy ======
__global__ __launch_bounds__(256) void lstm_elem_kernel(
    const float* __restrict__ gates, const float* __restrict__ c0,
    float* __restrict__ h_out, float* __restrict__ c_out, ushort* __restrict__ h_bf,
    float* __restrict__ pmn, float* __restrict__ pmx)
{
  const int i = blockIdx.x, d = threadIdx.x;
  const float* g = gates + (size_t)i * 1024;
  const float xi = g[d], xf = g[256 + d], xg = g[512 + d], xo = g[768 + d];
  const float c = c0[(size_t)i * 256 + d];
  const float si = 1.0f / (1.0f + expf(-xi));
  const float sf = 1.0f / (1.0f + expf(-xf));
  const float so = 1.0f / (1.0f + expf(-xo));
  const float c2 = sf * c + si * tanhf(xg);
  const float h2 = so * tanhf(c2);
  h_out[(size_t)i * 256 + d] = h2;
  c_out[(size_t)i * 256 + d] = c2;
  h_bf[(size_t)i * 256 + d] = f2b(h2);
  float mn = h2, mx = h2;
  #pragma unroll
  for (int o = 32; o > 0; o >>= 1) {
    mn = fminf(mn, __shfl_xor(mn, o));
    mx = fmaxf(mx, __shfl_xor(mx, o));
  }
  __shared__ float smn[4], smx[4];
  if ((d & 63) == 0) { smn[d >> 6] = mn; smx[d >> 6] = mx; }
  __syncthreads();
  if (d == 0) {
    pmn[i] = fminf(fminf(smn[0], smn[1]), fminf(smn[2], smn[3]));
    pmx[i] = fmaxf(fmaxf(smx[0], smx[1]), fmaxf(smx[2], smx[3]));
  }
}

// === fake-quant (fused global min/max from partials) -> bf16 + loss partial ===
__global__ __launch_bounds__(256) void quant_kernel(
    const float4* __restrict__ x, ushort* __restrict__ q, int n4,
    const float* __restrict__ pmn, const float* __restrict__ pmx, int np,
    float* __restrict__ part)
{
  __shared__ float smn[4], smx[4], sl[4], bmn, bmx;
  float mn = 3.0e38f, mx = -3.0e38f;
  for (int i = threadIdx.x; i < np; i += 256) {
    mn = fminf(mn, pmn[i]); mx = fmaxf(mx, pmx[i]);
  }
  #pragma unroll
  for (int o = 32; o > 0; o >>= 1) {
    mn = fminf(mn, __shfl_xor(mn, o));
    mx = fmaxf(mx, __shfl_xor(mx, o));
  }
  if ((threadIdx.x & 63) == 0) { smn[threadIdx.x >> 6] = mn; smx[threadIdx.x >> 6] = mx; }
  __syncthreads();
  if (threadIdx.x == 0) {
    bmn = fminf(fminf(smn[0], smn[1]), fminf(smn[2], smn[3]));
    bmx = fmaxf(fmaxf(smx[0], smx[1]), fmaxf(smx[2], smx[3]));
  }
  __syncthreads();
  mn = bmn; mx = bmx;
  if (mn == mx) { mn -= 0.01f; mx += 0.01f; }
  const float scale = (mx - mn) / 255.0f;
  const float zp = rintf(-mn / scale);
  float lsum = 0.0f;
  for (int idx = blockIdx.x * 256 + threadIdx.x; idx < n4; idx += gridDim.x * 256) {
    const float4 t = x[idx];
    float d0, d1, d2, d3;
    { float qq = fminf(fmaxf(rintf(t.x / scale + zp), 0.0f), 255.0f);
      d0 = (qq - zp) * scale; lsum += log2f(510.0f * fabsf(d0) + 1.0f); }
    { float qq = fminf(fmaxf(rintf(t.y / scale + zp), 0.0f), 255.0f);
      d1 = (qq - zp) * scale; lsum += log2f(510.0f * fabsf(d1) + 1.0f); }
    { float qq = fminf(fmaxf(rintf(t.z / scale + zp), 0.0f), 255.0f);
      d2 = (qq - zp) * scale; lsum += log2f(510.0f * fabsf(d2) + 1.0f); }
    { float qq = fminf(fmaxf(rintf(t.w / scale + zp), 0.0f), 255.0f);
      d3 = (qq - zp) * scale; lsum += log2f(510.0f * fabsf(d3) + 1.0f); }
    ushort4 o; o.x = f2b(d0); o.y = f2b(d1); o.z = f2b(d2); o.w = f2b(d3);
    *(ushort4*)(q + (size_t)idx * 4) = o;
  }
  #pragma unroll
  for (int o = 32; o > 0; o >>= 1) lsum += __shfl_xor(lsum, o);
  if ((threadIdx.x & 63) == 0) sl[threadIdx.x >> 6] = lsum;
  __syncthreads();
  if (threadIdx.x == 0) part[blockIdx.x] = sl[0] + sl[1] + sl[2] + sl[3];
}

// ==================== GAT attention coefficients ====================
__global__ __launch_bounds__(256) void cicj1_kernel(
    const float* __restrict__ h1, const float* __restrict__ ai, const float* __restrict__ aj,
    float* __restrict__ ci, float* __restrict__ cj)
{
  const int w = threadIdx.x >> 6, lane = threadIdx.x & 63;
  const int i = blockIdx.x * 4 + w;
  #pragma unroll
  for (int hd = 0; hd < 4; ++hd) {
    const float v = h1[(size_t)i * 256 + hd * 64 + lane];
    float pi = v * ai[hd * 64 + lane];
    float pj = v * aj[hd * 64 + lane];
    #pragma unroll
    for (int o = 32; o > 0; o >>= 1) { pi += __shfl_xor(pi, o); pj += __shfl_xor(pj, o); }
    if (lane == 0) { ci[hd * 4096 + i] = pi; cj[hd * 4096 + i] = pj; }
  }
}

__global__ __launch_bounds__(256) void cicj2_kernel(
    const float* __restrict__ h2, const float* __restrict__ ai, const float* __restrict__ aj,
    float* __restrict__ ci, float* __restrict__ cj)
{
  const int w = threadIdx.x >> 6, lane = threadIdx.x & 63;
  const int i = blockIdx.x * 4 + w;
  float pi = 0.f, pj = 0.f;
  #pragma unroll
  for (int r = 0; r < 4; ++r) {
    const float v = h2[(size_t)i * 256 + r * 64 + lane];
    pi += v * ai[r * 64 + lane];
    pj += v * aj[r * 64 + lane];
  }
  #pragma unroll
  for (int o = 32; o > 0; o >>= 1) { pi += __shfl_xor(pi, o); pj += __shfl_xor(pj, o); }
  if (lane == 0) { ci[i] = pi; cj[i] = pj; }
}

// =================== rank sort (per head, n=4096) ===================
__global__ __launch_bounds__(1024) void rank_sort_kernel(
    const float* __restrict__ c, float* __restrict__ sc, int* __restrict__ pm)
{
  __shared__ float lc[4096];
  __shared__ int scnt[16][64];
  const int head = blockIdx.x >> 6;
  const int seg = blockIdx.x & 63;
  const float* ch = c + head * 4096;
  for (int idx = threadIdx.x; idx < 4096; idx += 1024) lc[idx] = ch[idx];
  __syncthreads();
  const int jl = threadIdx.x & 63;
  const int kg = threadIdx.x >> 6;
  const int j = seg * 64 + jl;
  const float my = lc[j];
  int cnt = 0;
  const int k0 = kg * 256;
  #pragma unroll 8
  for (int k = k0; k < k0 + 256; ++k) {
    const float ck = lc[k];
    cnt += (ck < my || (ck == my && k < j)) ? 1 : 0;
  }
  scnt[kg][jl] = cnt;
  __syncthreads();
  if (threadIdx.x < 64) {
    int rank = 0;
    #pragma unroll
    for (int g = 0; g < 16; ++g) rank += scnt[g][threadIdx.x];
    const int jj = seg * 64 + threadIdx.x;
    sc[head * 4096 + rank] = lc[jj];
    pm[head * 4096 + rank] = jj;
  }
}

// ======= local scan (GAT1): 2 waves/block, wave0=PV asc, wave1=PU desc =======
__global__ __launch_bounds__(128) void local_scan1(
    const float* __restrict__ h1, const float* __restrict__ sc, const int* __restrict__ pm,
    float* __restrict__ PUl, float* __restrict__ PVl,
    float* __restrict__ dUl, float* __restrict__ dVl,
    float* __restrict__ cku, float* __restrict__ ckv,
    float* __restrict__ ckus, float* __restrict__ ckvs)
{
  const int head = blockIdx.x >> 6;
  const int chunk = blockIdx.x & 63;
  const int wave = threadIdx.x >> 6;
  const int lane = threadIdx.x & 63;
  const float cmax = sc[head * 4096 + 4095];
  const int base = head * 4096 + chunk * 64;
  const float cv = sc[base + lane];
  const float u = expf(cv - cmax);
  const float v = expf(0.2f * (cv - cmax));
  const int myj = pm[base + lane];
  const float* hrow = h1 + head * 64 + lane;
  if (wave == 0) {
    // scalar wave scans
    float iu = u, iv = v;
    #pragma unroll
    for (int o = 1; o < 64; o <<= 1) {
      const float tu = __shfl_up(iu, o), tv = __shfl_up(iv, o);
      if (lane >= o) { iu += tu; iv += tv; }
    }
    const float totU = __shfl(iu, 63), totV = __shfl(iv, 63);
    dVl[base + lane] = iv - v;
    dUl[base + lane] = totU - (iu - u);
    if (lane == 0) { ckus[head * 64 + chunk] = totU; ckvs[head * 64 + chunk] = totV; }
    float accV = 0.f;
    #pragma unroll 16
    for (int k = 0; k < 64; ++k) {
      const float vk = __shfl(v, k);
      const int j = __shfl(myj, k);
      PVl[(size_t)(base + k) * 64 + lane] = accV;
      accV += vk * hrow[(size_t)j * 256];
    }
    ckv[(head * 64 + chunk) * 64 + lane] = accV;
  } else {
    float accU = 0.f;
    #pragma unroll 16
    for (int k = 63; k >= 0; --k) {
      const float uk = __shfl(u, k);
      const int j = __shfl(myj, k);
      accU += uk * hrow[(size_t)j * 256];
      PUl[(size_t)(base + k) * 64 + lane] = accU;
    }
    cku[(head * 64 + chunk) * 64 + lane] = accU;
  }
}

// === local scan (GAT2, g=256): grid (colgrp=2, chunk=64); waves 0-1 PV, 2-3 PU ===
__global__ __launch_bounds__(256) void local_scan2(
    const float* __restrict__ h2, const float* __restrict__ sc, const int* __restrict__ pm,
    float* __restrict__ PUl, float* __restrict__ PVl,
    float* __restrict__ dUl, float* __restrict__ dVl,
    float* __restrict__ cku, float* __restrict__ ckv,
    float* __restrict__ ckus, float* __restrict__ ckvs)
{
  __shared__ float su[64], sv[64];
  __shared__ int sj[64];
  const int chunk = blockIdx.y;
  const int colgrp = blockIdx.x;
  const int tid = threadIdx.x;
  const int wave = tid >> 6, lane = tid & 63;
  const float cmax = sc[4095];
  const int base = chunk * 64;
  if (tid < 64) {
    const float cv = sc[base + tid];
    const float u = expf(cv - cmax);
    const float v = expf(0.2f * (cv - cmax));
    su[tid] = u; sv[tid] = v; sj[tid] = pm[base + tid];
    if (colgrp == 0) {
      float iu = u, iv = v;
      #pragma unroll
      for (int o = 1; o < 64; o <<= 1) {
        const float tu = __shfl_up(iu, o), tv = __shfl_up(iv, o);
        if (lane >= o) { iu += tu; iv += tv; }
      }
      const float totU = __shfl(iu, 63), totV = __shfl(iv, 63);
      dVl[base + lane] = iv - v;
      dUl[base + lane] = totU - (iu - u);
      if (lane == 0) { ckus[chunk] = totU; ckvs[chunk] = totV; }
    }
  }
  __syncthreads();
  const int col = colgrp * 128 + (wave & 1) * 64 + lane;
  if (wave < 2) {
    float accV = 0.f;
    #pragma unroll 16
    for (int k = 0; k < 64; ++k) {
      PVl[(size_t)(base + k) * 256 + col] = accV;
      accV += sv[k] * h2[(size_t)sj[k] * 256 + col];
    }
    ckv[chunk * 256 + col] = accV;
  } else {
    float accU = 0.f;
    #pragma unroll 16
    for (int k = 63; k >= 0; --k) {
      accU += su[k] * h2[(size_t)sj[k] * 256 + col];
      PUl[(size_t)(base + k) * 256 + col] = accU;
    }
    cku[chunk * 256 + col] = accU;
  }
}

// ======= chunk prefix/suffix via lane=chunk wave scans =======
__global__ __launch_bounds__(256) void prefix1_kernel(
    const float* __restrict__ cku, const float* __restrict__ ckv,
    const float* __restrict__ ckus, const float* __restrict__ ckvs,
    float* __restrict__ sufU, float* __restrict__ prefV,
    float* __restrict__ sufUs, float* __restrict__ prefVs)
{
  const int head = blockIdx.x;
  const int wave = threadIdx.x >> 6, lane = threadIdx.x & 63;
  for (int g = wave; g < 64; g += 4) {
    const float vv = ckv[(head * 64 + lane) * 64 + g];
    const float uu = cku[(head * 64 + lane) * 64 + g];
    float iv = vv, iu = uu;
    #pragma unroll
    for (int o = 1; o < 64; o <<= 1) {
      const float tv = __shfl_up(iv, o), tu = __shfl_up(iu, o);
      if (lane >= o) { iv += tv; iu += tu; }
    }
    prefV[(head * 65 + lane) * 64 + g] = iv - vv;
    const float totU = __shfl(iu, 63);
    sufU[(head * 65 + lane) * 64 + g] = totU - iu + uu;
    if (lane == 63) {
      prefV[(head * 65 + 64) * 64 + g] = iv;
      sufU[(head * 65 + 64) * 64 + g] = 0.f;
    }
  }
  if (wave == 0) {
    const float vs = ckvs[head * 64 + lane];
    const float us = ckus[head * 64 + lane];
    float iv = vs, iu = us;
    #pragma unroll
    for (int o = 1; o < 64; o <<= 1) {
      const float tv = __shfl_up(iv, o), tu = __shfl_up(iu, o);
      if (lane >= o) { iv += tv; iu += tu; }
    }
    prefVs[head * 65 + lane] = iv - vs;
    const float totU = __shfl(iu, 63);
    sufUs[head * 65 + lane] = totU - iu + us;
    if (lane == 63) {
      prefVs[head * 65 + 64] = iv;
      sufUs[head * 65 + 64] = 0.f;
    }
  }
}

__global__ __launch_bounds__(256) void prefix2_kernel(
    const float* __restrict__ cku, const float* __restrict__ ckv,
    const float* __restrict__ ckus, const float* __restrict__ ckvs,
    float* __restrict__ sufU, float* __restrict__ prefV,
    float* __restrict__ sufUs, float* __restrict__ prefVs)
{
  const int wave = threadIdx.x >> 6, lane = threadIdx.x & 63;
  for (int cc = 0; cc < 64; ++cc) {
    const int col = wave * 64 + cc;
    const float vv = ckv[lane * 256 + col];
    const float uu = cku[lane * 256 + col];
    float iv = vv, iu = uu;
    #pragma unroll
    for (int o = 1; o < 64; o <<= 1) {
      const float tv = __shfl_up(iv, o), tu = __shfl_up(iu, o);
      if (lane >= o) { iv += tv; iu += tu; }
    }
    prefV[lane * 256 + col] = iv - vv;
    const float totU = __shfl(iu, 63);
    sufU[lane * 256 + col] = totU - iu + uu;
    if (lane == 63) {
      prefV[64 * 256 + col] = iv;
      sufU[64 * 256 + col] = 0.f;
    }
  }
  if (wave == 0) {
    const float vs = ckvs[lane];
    const float us = ckus[lane];
    float iv = vs, iu = us;
    #pragma unroll
    for (int o = 1; o < 64; o <<= 1) {
      const float tv = __shfl_up(iv, o), tu = __shfl_up(iu, o);
      if (lane >= o) { iv += tv; iu += tu; }
    }
    prefVs[lane] = iv - vs;
    const float totU = __shfl(iu, 63);
    sufUs[lane] = totU - iu + us;
    if (lane == 63) { prefVs[64] = iv; sufUs[64] = 0.f; }
  }
}

// ====== GAT1 combine: pure lookup. out = elu(att@h + b1) + minmax ======
__global__ __launch_bounds__(256) void combine1_kernel(
    const float* __restrict__ ci, const float* __restrict__ sc,
    const float* __restrict__ sufU, const float* __restrict__ prefV,
    const float* __restrict__ sufUs, const float* __restrict__ prefVs,
    const float* __restrict__ PUl, const float* __restrict__ PVl,
    const float* __restrict__ dUl, const float* __restrict__ dVl,
    const float* __restrict__ b1, float* __restrict__ out,
    float* __restrict__ pmn, float* __restrict__ pmx)
{
  const int i = blockIdx.x;
  const int head = threadIdx.x >> 6;
  const int lane = threadIdx.x & 63;
  const float* sch = sc + head * 4096;
  const float civ = ci[head * 4096 + i];
  const float cmax = sch[4095];
  const float sarg = civ + cmax;
  const float m = sarg > 0.f ? sarg : 0.2f * sarg;
  const float Af = expf(sarg - m);
  const float Bf = expf(0.2f * sarg - m);
  const float t = -civ;
  int lo = 0, hi = 4096;
  while (lo < hi) {
    const int mid = (lo + hi) >> 1;
    if (sch[mid] > t) hi = mid; else lo = mid + 1;
  }
  const int s = lo;
  float accP, accN, dP, dN;
  if (s == 4096) {
    accP = 0.f; dP = 0.f;
    accN = prefV[(head * 65 + 64) * 64 + lane];
    dN = prefVs[head * 65 + 64];
  } else {
    const int cs = s >> 6;
    accP = sufU[(head * 65 + cs + 1) * 64 + lane] + PUl[(size_t)(head * 4096 + s) * 64 + lane];
    accN = prefV[(head * 65 + cs) * 64 + lane] + PVl[(size_t)(head * 4096 + s) * 64 + lane];
    dP = sufUs[head * 65 + cs + 1] + dUl[head * 4096 + s];
    dN = prefVs[head * 65 + cs] + dVl[head * 4096 + s];
  }
  const float num = Af * accP + Bf * accN;
  const float den = Af * dP + Bf * dN;
  const float o = num / den + b1[head * 64 + lane];
  const float oe = o > 0.f ? o : expm1f(o);
  out[(size_t)i * 256 + head * 64 + lane] = oe;
  float mn = oe, mx = oe;
  #pragma unroll
  for (int of = 32; of > 0; of >>= 1) {
    mn = fminf(mn, __shfl_xor(mn, of));
    mx = fmaxf(mx, __shfl_xor(mx, of));
  }
  __shared__ float smn[4], smx[4];
  if (lane == 0) { smn[head] = mn; smx[head] = mx; }
  __syncthreads();
  if (threadIdx.x == 0) {
    pmn[i] = fminf(fminf(smn[0], smn[1]), fminf(smn[2], smn[3]));
    pmx[i] = fmaxf(fmaxf(smx[0], smx[1]), fmaxf(smx[2], smx[3]));
  }
}

// ========= GAT2 combine: pure lookup, writes bf16 =========
__global__ __launch_bounds__(256) void combine2_kernel(
    const float* __restrict__ ci, const float* __restrict__ sc,
    const float* __restrict__ sufU, const float* __restrict__ prefV,
    const float* __restrict__ sufUs, const float* __restrict__ prefVs,
    const float* __restrict__ PUl, const float* __restrict__ PVl,
    const float* __restrict__ dUl, const float* __restrict__ dVl,
    const float* __restrict__ b2, ushort* __restrict__ outb)
{
  const int i = blockIdx.x;
  const int col = threadIdx.x;
  const float civ = ci[i];
  const float cmax = sc[4095];
  const float sarg = civ + cmax;
  const float m = sarg > 0.f ? sarg : 0.2f * sarg;
  const float Af = expf(sarg - m);
  const float Bf = expf(0.2f * sarg - m);
  const float t = -civ;
  int lo = 0, hi = 4096;
  while (lo < hi) {
    const int mid = (lo + hi) >> 1;
    if (sc[mid] > t) hi = mid; else lo = mid + 1;
  }
  const int s = lo;
  float accP, accN, dP, dN;
  if (s == 4096) {
    accP = 0.f; dP = 0.f;
    accN = prefV[64 * 256 + col];
    dN = prefVs[64];
  } else {
    const int cs = s >> 6;
    accP = sufU[(cs + 1) * 256 + col] + PUl[(size_t)s * 256 + col];
    accN = prefV[cs * 256 + col] + PVl[(size_t)s * 256 + col];
    dP = sufUs[cs + 1] + dUl[s];
    dN = prefVs[cs] + dVl[s];
  }
  const float num = Af * accP + Bf * accN;
  const float den = Af * dP + Bf * dN;
  outb[(size_t)i * 256 + col] = f2b(num / den + b2[col]);
}

// ===== log-softmax + value extract; block 4096 = loss finalization =====
__global__ __launch_bounds__(64) void logsoftmax_kernel(
    const float* __restrict__ logits_ext, float* __restrict__ out,
    float* __restrict__ out_value,
    const float* __restrict__ p1, const float* __restrict__ p2,
    float* __restrict__ out_loss)
{
  const int i = blockIdx.x, lane = threadIdx.x;
  if (i == 4096) {
    float s = 0.f;
    #pragma unroll
    for (int k = 0; k < 4; ++k) s += p1[lane + k * 64] + p2[lane + k * 64];
    #pragma unroll
    for (int o = 32; o > 0; o >>= 1) s += __shfl_xor(s, o);
    if (lane == 0) out_loss[0] = s;
    return;
  }
  const float x = logits_ext[(size_t)i * 128 + lane];
  float mx = x;
  #pragma unroll
  for (int o = 32; o > 0; o >>= 1) mx = fmaxf(mx, __shfl_xor(mx, o));
  float e = expf(x - mx);
  #pragma unroll
  for (int o = 32; o > 0; o >>= 1) e += __shfl_xor(e, o);
  out[(size_t)i * 64 + lane] = x - mx - logf(e);
  if (lane == 0) out_value[i] = logits_ext[(size_t)i * 128 + 64];
}

// ============================ launch ============================
extern "C" void kernel_launch(void* const* d_in, const int* in_sizes, int n_in,
                              void* d_out, int out_size, void* d_ws, size_t ws_size,
                              hipStream_t stream) {
  const float* obs  = (const float*)d_in[0];
  const float* h0   = (const float*)d_in[1];
  const float* c0   = (const float*)d_in[2];
  const float* Wobs = (const float*)d_in[3];
  const float* bobs = (const float*)d_in[4];
  const float* Wih  = (const float*)d_in[5];
  const float* Whh  = (const float*)d_in[6];
  const float* bih  = (const float*)d_in[7];
  const float* bhh  = (const float*)d_in[8];
  const float* W1   = (const float*)d_in[9];
  const float* ai1  = (const float*)d_in[10];
  const float* aj1  = (const float*)d_in[11];
  const float* b1   = (const float*)d_in[12];
  const float* W2   = (const float*)d_in[13];
  const float* ai2  = (const float*)d_in[14];
  const float* aj2  = (const float*)d_in[15];
  const float* b2   = (const float*)d_in[16];
  const float* Wv   = (const float*)d_in[17];
  const float* bv   = (const float*)d_in[18];
  const float* Wa   = (const float*)d_in[19];
  const float* ba   = (const float*)d_in[20];

  float* out       = (float*)d_out;
  float* out_logp  = out;                 // [1,4096,64]
  float* out_value = out + 262144;        // [4096,1]
  float* out_h     = out + 266240;        // [4096,256]
  float* out_c     = out + 1314816;       // [4096,256]
  float* out_loss  = out + 2363392;       // scalar

  char* ws = (char*)d_ws;
  float* part1  = (float*)(ws + 256);
  float* part2  = (float*)(ws + 1280);
  float* pmn    = (float*)(ws + 2304);
  float* pmx    = (float*)(ws + 18688);
  const size_t MB = 1048576;
  const size_t base = 35072;
  ushort* obs_bf  = (ushort*)(ws + base);
  ushort* h0_bf   = (ushort*)(ws + base + 2 * MB);
  ushort* Wih_bf  = (ushort*)(ws + base + 4 * MB);
  ushort* Whh_bf  = (ushort*)(ws + base + 4 * MB + 524288);
  ushort* WobsT   = (ushort*)(ws + base + 5 * MB);
  ushort* W1T     = (ushort*)(ws + base + 5 * MB + 131072);
  ushort* W2T     = (ushort*)(ws + base + 5 * MB + 262144);
  ushort* WaTe    = (ushort*)(ws + base + 5 * MB + 393216);
  float*  bias_ext= (float*) (ws + base + 5 * MB + 524288);
  float*  bias12  = (float*) (ws + base + 5 * MB + 525312);
  ushort* enc_bf  = (ushort*)(ws + base + 6 * MB);
  ushort* h_bf    = (ushort*)(ws + base + 8 * MB);
  ushort* comm_q1 = (ushort*)(ws + base + 10 * MB);
  ushort* comm_q2 = (ushort*)(ws + base + 12 * MB);
  ushort* comm2_bf= (ushort*)(ws + base + 14 * MB);
  float*  gates   = (float*) (ws + base + 16 * MB);       // 16 MB, reused:
  float*  h1      = gates;
  float*  comm1e  = (float*)((char*)gates + 4 * MB);
  float*  h2b     = (float*)((char*)gates + 8 * MB);
  float*  logits  = (float*)((char*)gates + 12 * MB);
  size_t so = base + 32 * MB;
  auto alloc = [&](size_t bytes) { size_t r = so; so += (bytes + 255) & ~255ull; return (char*)ws + r; };
  float* ci1    = (float*)alloc(4 * 4096 * 4);
  float* cj1    = (float*)alloc(4 * 4096 * 4);
  float* sc1    = (float*)alloc(4 * 4096 * 4);
  int*   pm1    = (int*)  alloc(4 * 4096 * 4);
  float* cku1   = (float*)alloc(4 * 64 * 64 * 4);
  float* ckv1   = (float*)alloc(4 * 64 * 64 * 4);
  float* ckus1  = (float*)alloc(4 * 64 * 4);
  float* ckvs1  = (float*)alloc(4 * 64 * 4);
  float* sufU1  = (float*)alloc(4 * 65 * 64 * 4);
  float* prefV1 = (float*)alloc(4 * 65 * 64 * 4);
  float* sufUs1 = (float*)alloc(4 * 65 * 4);
  float* prefVs1= (float*)alloc(4 * 65 * 4);
  float* ci2    = (float*)alloc(4096 * 4);
  float* cj2    = (float*)alloc(4096 * 4);
  float* sc2    = (float*)alloc(4096 * 4);
  int*   pm2    = (int*)  alloc(4096 * 4);
  float* cku2   = (float*)alloc(64 * 256 * 4);
  float* ckv2   = (float*)alloc(64 * 256 * 4);
  float* ckus2  = (float*)alloc(64 * 4);
  float* ckvs2  = (float*)alloc(64 * 4);
  float* sufU2  = (float*)alloc(65 * 256 * 4);
  float* prefV2 = (float*)alloc(65 * 256 * 4);
  float* sufUs2 = (float*)alloc(65 * 4);
  float* prefVs2= (float*)alloc(65 * 4);
  float* PUl    = (float*)alloc(4 * 4096 * 64 * 4);   // 4 MB
  float* PVl    = (float*)alloc(4 * 4096 * 64 * 4);   // 4 MB
  float* dUl    = (float*)alloc(4 * 4096 * 4);
  float* dVl    = (float*)alloc(4 * 4096 * 4);

  const dim3 b256(256);
  const int N4 = 262144;

  prep_kernel<<<dim3(1477), b256, 0, stream>>>(
      obs, obs_bf, h0, h0_bf, Wih, Wih_bf, Whh, Whh_bf,
      Wobs, WobsT, W1, W1T, W2, W2T,
      Wa, Wv, ba, bv, bih, bhh, WaTe, bias_ext, bias12);
  mfma_gemm<64, 64, true><<<dim3(4, 64), b256, 0, stream>>>(
      obs_bf, 256, WobsT, 256, 256, nullptr, 0, nullptr, 0, 0, bobs, enc_bf, 256);
  mfma_gemm<128, 128, false><<<dim3(8, 32), b256, 0, stream>>>(
      enc_bf, 256, Wih_bf, 256, 256, h0_bf, 256, Whh_bf, 256, 256, bias12, gates, 1024);
  lstm_elem_kernel<<<dim3(4096), b256, 0, stream>>>(gates, c0, out_h, out_c, h_bf, pmn, pmx);
  quant_kernel<<<dim3(256), b256, 0, stream>>>(
      (const float4*)out_h, comm_q1, N4, pmn, pmx, 4096, part1);
  // ---- GAT1 ----
  mfma_gemm<64, 64, false><<<dim3(4, 64), b256, 0, stream>>>(
      comm_q1, 256, W1T, 256, 256, nullptr, 0, nullptr, 0, 0, nullptr, h1, 256);
  cicj1_kernel<<<dim3(1024), b256, 0, stream>>>(h1, ai1, aj1, ci1, cj1);
  rank_sort_kernel<<<dim3(256), dim3(1024), 0, stream>>>(cj1, sc1, pm1);
  local_scan1<<<dim3(256), dim3(128), 0, stream>>>(h1, sc1, pm1,
      PUl, PVl, dUl, dVl, cku1, ckv1, ckus1, ckvs1);
  prefix1_kernel<<<dim3(4), b256, 0, stream>>>(cku1, ckv1, ckus1, ckvs1,
                                               sufU1, prefV1, sufUs1, prefVs1);
  combine1_kernel<<<dim3(4096), b256, 0, stream>>>(ci1, sc1,
      sufU1, prefV1, sufUs1, prefVs1, PUl, PVl, dUl, dVl, b1, comm1e, pmn, pmx);
  quant_kernel<<<dim3(256), b256, 0, stream>>>(
      (const float4*)comm1e, comm_q2, N4, pmn, pmx, 4096, part2);
  // ---- GAT2 ----
  mfma_gemm<64, 64, false><<<dim3(4, 64), b256, 0, stream>>>(
      comm_q2, 256, W2T, 256, 256, nullptr, 0, nullptr, 0, 0, nullptr, h2b, 256);
  cicj2_kernel<<<dim3(1024), b256, 0, stream>>>(h2b, ai2, aj2, ci2, cj2);
  rank_sort_kernel<<<dim3(64), dim3(1024), 0, stream>>>(cj2, sc2, pm2);
  local_scan2<<<dim3(2, 64), b256, 0, stream>>>(h2b, sc2, pm2,
      PUl, PVl, dUl, dVl, cku2, ckv2, ckus2, ckvs2);
  prefix2_kernel<<<dim3(1), b256, 0, stream>>>(cku2, ckv2, ckus2, ckvs2,
                                               sufU2, prefV2, sufUs2, prefVs2);
  combine2_kernel<<<dim3(4096), b256, 0, stream>>>(ci2, sc2,
      sufU2, prefV2, sufUs2, prefVs2, PUl, PVl, dUl, dVl, b2, comm2_bf);
  // ---- heads ----
  mfma_gemm<64, 64, false><<<dim3(2, 64), b256, 0, stream>>>(
      h_bf, 256, WaTe, 512, 256, comm2_bf, 256, WaTe + 256, 512, 256,
      bias_ext, logits, 128);
  logsoftmax_kernel<<<dim3(4097), dim3(64), 0, stream>>>(
      logits, out_logp, out_value, part1, part2, out_loss);
}

// Round 6
// 258.253 us; speedup vs baseline: 1.1771x; 1.1771x over previous
//
#include <hip/hip_runtime.h>
#include <math.h>

typedef __attribute__((ext_vector_type(8))) short short8;
typedef __attribute__((ext_vector_type(4))) float floatx4;

__device__ __forceinline__ ushort f2b(float f) {
  unsigned u = __float_as_uint(f);
  unsigned r = u + 0x7FFFu + ((u >> 16) & 1u);
  return (ushort)(r >> 16);
}

// ====== mega prep: convert obs/h0/Wih/Whh + transpose Wobs/W1/W2 + misc ======
__global__ __launch_bounds__(256) void prep_kernel(
    const float* __restrict__ obs, ushort* __restrict__ obs_bf,
    const float* __restrict__ h0, ushort* __restrict__ h0_bf,
    const float* __restrict__ Wih, ushort* __restrict__ Wih_bf,
    const float* __restrict__ Whh, ushort* __restrict__ Whh_bf,
    const float* __restrict__ Wobs, ushort* __restrict__ WobsT,
    const float* __restrict__ W1, ushort* __restrict__ W1T,
    const float* __restrict__ W2, ushort* __restrict__ W2T,
    const float* __restrict__ Wa, const float* __restrict__ Wv,
    const float* __restrict__ ba, const float* __restrict__ bv,
    const float* __restrict__ bih, const float* __restrict__ bhh,
    ushort* __restrict__ WaTe, float* __restrict__ bias_ext, float* __restrict__ bias12)
{
  __shared__ float tile[32][33];
  const int bid = blockIdx.x;
  const int tid = threadIdx.x;
  if (bid < 1024) {
    const int q0 = 262144, q1 = 262144, q2 = 65536, q3 = 65536;
    const int tot = q0 + q1 + q2 + q3;
    for (int idx = bid * 256 + tid; idx < tot; idx += 1024 * 256) {
      const float* s; ushort* d; int i = idx;
      if (i < q0) { s = obs; d = obs_bf; }
      else if ((i -= q0) < q1) { s = h0; d = h0_bf; }
      else if ((i -= q1) < q2) { s = Wih; d = Wih_bf; }
      else { i -= q2; s = Whh; d = Whh_bf; }
      const float4 v = *(const float4*)(s + (size_t)i * 4);
      ushort4 o; o.x = f2b(v.x); o.y = f2b(v.y); o.z = f2b(v.z); o.w = f2b(v.w);
      *(ushort4*)(d + (size_t)i * 4) = o;
    }
  } else if (bid < 1216) {
    const int t = bid - 1024;
    const int mat = t >> 6, sub = t & 63;
    const float* in = mat == 0 ? Wobs : (mat == 1 ? W1 : W2);
    ushort* outp = mat == 0 ? WobsT : (mat == 1 ? W1T : W2T);
    const int c0 = (sub & 7) * 32, r0 = (sub >> 3) * 32;
    const int tx = tid & 31, ty = tid >> 5;
    #pragma unroll
    for (int p = 0; p < 32; p += 8)
      tile[ty + p][tx] = in[(size_t)(r0 + ty + p) * 256 + c0 + tx];
    __syncthreads();
    #pragma unroll
    for (int p = 0; p < 32; p += 8)
      outp[(size_t)(c0 + ty + p) * 256 + r0 + tx] = f2b(tile[tx][ty + p]);
  } else {
    const int idx = (bid - 1216) * 256 + tid;
    if (idx < 65536) {
      const int n = idx >> 9, k = idx & 511;
      const float v = n < 64 ? Wa[(size_t)k * 64 + n] : (n == 64 ? Wv[k] : 0.0f);
      WaTe[idx] = f2b(v);
    } else if (idx < 65536 + 128) {
      const int n = idx - 65536;
      bias_ext[n] = n < 64 ? ba[n] : (n == 64 ? bv[0] : 0.0f);
    } else if (idx < 65536 + 128 + 1024) {
      const int n = idx - 65536 - 128;
      bias12[n] = bih[n] + bhh[n];
    }
  }
}

// ===== MFMA GEMM: C[M,N] = A1@B1^T + A2@B2^T + bias (all NT, bf16 in) =====
template<int BM, int BN, bool OUT_BF16>
__global__ __launch_bounds__(256) void mfma_gemm(
    const ushort* __restrict__ A1, int lda1,
    const ushort* __restrict__ B1, int ldb1, int K1,
    const ushort* __restrict__ A2, int lda2,
    const ushort* __restrict__ B2, int ldb2, int K2,
    const float* __restrict__ bias,
    void* __restrict__ Cv, int N)
{
  constexpr int LDT = 40;
  __shared__ __align__(16) ushort As[BM * LDT];
  __shared__ __align__(16) ushort Bs[BN * LDT];
  const int tid = threadIdx.x;
  const int wave = tid >> 6, lane = tid & 63;
  const int wr = wave >> 1, wc = wave & 1;
  const int m0 = blockIdx.y * BM, n0 = blockIdx.x * BN;
  constexpr int MI = BM / 32;
  constexpr int NI = BN / 32;
  floatx4 acc[MI][NI] = {};
  const int r = tid >> 2, kq = tid & 3;
  const int lm = lane & 15, lq = lane >> 4;
  const int Ktot = K1 + K2;
  for (int k0 = 0; k0 < Ktot; k0 += 32) {
    const ushort* A; const ushort* B; int lda, ldb, kk;
    if (k0 < K1) { A = A1; B = B1; lda = lda1; ldb = ldb1; kk = k0; }
    else         { A = A2; B = B2; lda = lda2; ldb = ldb2; kk = k0 - K1; }
    #pragma unroll
    for (int p = 0; p < BM / 64; ++p) {
      const int rr = r + p * 64;
      *(float4*)&As[rr * LDT + kq * 8] =
          *(const float4*)&A[(size_t)(m0 + rr) * lda + kk + kq * 8];
    }
    #pragma unroll
    for (int p = 0; p < BN / 64; ++p) {
      const int rr = r + p * 64;
      *(float4*)&Bs[rr * LDT + kq * 8] =
          *(const float4*)&B[(size_t)(n0 + rr) * ldb + kk + kq * 8];
    }
    __syncthreads();
    short8 af[MI], bfr[NI];
    #pragma unroll
    for (int i = 0; i < MI; ++i)
      af[i] = *(const short8*)&As[(wr * (BM / 2) + i * 16 + lm) * LDT + lq * 8];
    #pragma unroll
    for (int j = 0; j < NI; ++j)
      bfr[j] = *(const short8*)&Bs[(wc * (BN / 2) + j * 16 + lm) * LDT + lq * 8];
    #pragma unroll
    for (int i = 0; i < MI; ++i)
      #pragma unroll
      for (int j = 0; j < NI; ++j)
        acc[i][j] = __builtin_amdgcn_mfma_f32_16x16x32_bf16(af[i], bfr[j], acc[i][j], 0, 0, 0);
    __syncthreads();
  }
  #pragma unroll
  for (int i = 0; i < MI; ++i) {
    #pragma unroll
    for (int j = 0; j < NI; ++j) {
      const int col = n0 + wc * (BN / 2) + j * 16 + lm;
      const float badd = bias ? bias[col] : 0.0f;
      #pragma unroll
      for (int t = 0; t < 4; ++t) {
        const int row = m0 + wr * (BM / 2) + i * 16 + lq * 4 + t;
        const float v = acc[i][j][t] + badd;
        if (OUT_BF16) ((ushort*)Cv)[(size_t)row * N + col] = f2b(v);
        else          ((float*)Cv)[(size_t)row * N + col] = v;
      }
    }
  }
}

// ====== LSTM cell + fused per-block min/max partials + bf16 h copy ======
__global__ __launch_bounds__(256) void lstm_elem_kernel(
    const float* __restrict__ gates, const float* __restrict__ c0,
    float* __restrict__ h_out, float* __restrict__ c_out, ushort* __restrict__ h_bf,
    float* __restrict__ pmn, float* __restrict__ pmx)
{
  const int i = blockIdx.x, d = threadIdx.x;
  const float* g = gates + (size_t)i * 1024;
  const float xi = g[d], xf = g[256 + d], xg = g[512 + d], xo = g[768 + d];
  const float c = c0[(size_t)i * 256 + d];
  const float si = 1.0f / (1.0f + expf(-xi));
  const float sf = 1.0f / (1.0f + expf(-xf));
  const float so = 1.0f / (1.0f + expf(-xo));
  const float c2 = sf * c + si * tanhf(xg);
  const float h2 = so * tanhf(c2);
  h_out[(size_t)i * 256 + d] = h2;
  c_out[(size_t)i * 256 + d] = c2;
  h_bf[(size_t)i * 256 + d] = f2b(h2);
  float mn = h2, mx = h2;
  #pragma unroll
  for (int o = 32; o > 0; o >>= 1) {
    mn = fminf(mn, __shfl_xor(mn, o));
    mx = fmaxf(mx, __shfl_xor(mx, o));
  }
  __shared__ float smn[4], smx[4];
  if ((d & 63) == 0) { smn[d >> 6] = mn; smx[d >> 6] = mx; }
  __syncthreads();
  if (d == 0) {
    pmn[i] = fminf(fminf(smn[0], smn[1]), fminf(smn[2], smn[3]));
    pmx[i] = fmaxf(fmaxf(smx[0], smx[1]), fmaxf(smx[2], smx[3]));
  }
}

// === fake-quant (fused global min/max from partials) -> bf16 + loss partial ===
__global__ __launch_bounds__(256) void quant_kernel(
    const float4* __restrict__ x, ushort* __restrict__ q, int n4,
    const float* __restrict__ pmn, const float* __restrict__ pmx, int np,
    float* __restrict__ part)
{
  __shared__ float smn[4], smx[4], sl[4], bmn, bmx;
  float mn = 3.0e38f, mx = -3.0e38f;
  for (int i = threadIdx.x; i < np; i += 256) {
    mn = fminf(mn, pmn[i]); mx = fmaxf(mx, pmx[i]);
  }
  #pragma unroll
  for (int o = 32; o > 0; o >>= 1) {
    mn = fminf(mn, __shfl_xor(mn, o));
    mx = fmaxf(mx, __shfl_xor(mx, o));
  }
  if ((threadIdx.x & 63) == 0) { smn[threadIdx.x >> 6] = mn; smx[threadIdx.x >> 6] = mx; }
  __syncthreads();
  if (threadIdx.x == 0) {
    bmn = fminf(fminf(smn[0], smn[1]), fminf(smn[2], smn[3]));
    bmx = fmaxf(fmaxf(smx[0], smx[1]), fmaxf(smx[2], smx[3]));
  }
  __syncthreads();
  mn = bmn; mx = bmx;
  if (mn == mx) { mn -= 0.01f; mx += 0.01f; }
  const float scale = (mx - mn) / 255.0f;
  const float zp = rintf(-mn / scale);
  float lsum = 0.0f;
  for (int idx = blockIdx.x * 256 + threadIdx.x; idx < n4; idx += gridDim.x * 256) {
    const float4 t = x[idx];
    float d0, d1, d2, d3;
    { float qq = fminf(fmaxf(rintf(t.x / scale + zp), 0.0f), 255.0f);
      d0 = (qq - zp) * scale; lsum += log2f(510.0f * fabsf(d0) + 1.0f); }
    { float qq = fminf(fmaxf(rintf(t.y / scale + zp), 0.0f), 255.0f);
      d1 = (qq - zp) * scale; lsum += log2f(510.0f * fabsf(d1) + 1.0f); }
    { float qq = fminf(fmaxf(rintf(t.z / scale + zp), 0.0f), 255.0f);
      d2 = (qq - zp) * scale; lsum += log2f(510.0f * fabsf(d2) + 1.0f); }
    { float qq = fminf(fmaxf(rintf(t.w / scale + zp), 0.0f), 255.0f);
      d3 = (qq - zp) * scale; lsum += log2f(510.0f * fabsf(d3) + 1.0f); }
    ushort4 o; o.x = f2b(d0); o.y = f2b(d1); o.z = f2b(d2); o.w = f2b(d3);
    *(ushort4*)(q + (size_t)idx * 4) = o;
  }
  #pragma unroll
  for (int o = 32; o > 0; o >>= 1) lsum += __shfl_xor(lsum, o);
  if ((threadIdx.x & 63) == 0) sl[threadIdx.x >> 6] = lsum;
  __syncthreads();
  if (threadIdx.x == 0) part[blockIdx.x] = sl[0] + sl[1] + sl[2] + sl[3];
}

// ==================== GAT attention coefficients ====================
__global__ __launch_bounds__(256) void cicj1_kernel(
    const float* __restrict__ h1, const float* __restrict__ ai, const float* __restrict__ aj,
    float* __restrict__ ci, float* __restrict__ cj)
{
  const int w = threadIdx.x >> 6, lane = threadIdx.x & 63;
  const int i = blockIdx.x * 4 + w;
  #pragma unroll
  for (int hd = 0; hd < 4; ++hd) {
    const float v = h1[(size_t)i * 256 + hd * 64 + lane];
    float pi = v * ai[hd * 64 + lane];
    float pj = v * aj[hd * 64 + lane];
    #pragma unroll
    for (int o = 32; o > 0; o >>= 1) { pi += __shfl_xor(pi, o); pj += __shfl_xor(pj, o); }
    if (lane == 0) { ci[hd * 4096 + i] = pi; cj[hd * 4096 + i] = pj; }
  }
}

__global__ __launch_bounds__(256) void cicj2_kernel(
    const float* __restrict__ h2, const float* __restrict__ ai, const float* __restrict__ aj,
    float* __restrict__ ci, float* __restrict__ cj)
{
  const int w = threadIdx.x >> 6, lane = threadIdx.x & 63;
  const int i = blockIdx.x * 4 + w;
  float pi = 0.f, pj = 0.f;
  #pragma unroll
  for (int r = 0; r < 4; ++r) {
    const float v = h2[(size_t)i * 256 + r * 64 + lane];
    pi += v * ai[r * 64 + lane];
    pj += v * aj[r * 64 + lane];
  }
  #pragma unroll
  for (int o = 32; o > 0; o >>= 1) { pi += __shfl_xor(pi, o); pj += __shfl_xor(pj, o); }
  if (lane == 0) { ci[i] = pi; cj[i] = pj; }
}

// =================== rank sort (per head, n=4096) ===================
__global__ __launch_bounds__(1024) void rank_sort_kernel(
    const float* __restrict__ c, float* __restrict__ sc, int* __restrict__ pm)
{
  __shared__ float lc[4096];
  __shared__ int scnt[16][64];
  const int head = blockIdx.x >> 6;
  const int seg = blockIdx.x & 63;
  const float* ch = c + head * 4096;
  for (int idx = threadIdx.x; idx < 4096; idx += 1024) lc[idx] = ch[idx];
  __syncthreads();
  const int jl = threadIdx.x & 63;
  const int kg = threadIdx.x >> 6;
  const int j = seg * 64 + jl;
  const float my = lc[j];
  int cnt = 0;
  const int k0 = kg * 256;
  #pragma unroll 8
  for (int k = k0; k < k0 + 256; ++k) {
    const float ck = lc[k];
    cnt += (ck < my || (ck == my && k < j)) ? 1 : 0;
  }
  scnt[kg][jl] = cnt;
  __syncthreads();
  if (threadIdx.x < 64) {
    int rank = 0;
    #pragma unroll
    for (int g = 0; g < 16; ++g) rank += scnt[g][threadIdx.x];
    const int jj = seg * 64 + threadIdx.x;
    sc[head * 4096 + rank] = lc[jj];
    pm[head * 4096 + rank] = jj;
  }
}

// ======= local scan (GAT1): 2 waves/block, wave0=PV asc, wave1=PU desc =======
__global__ __launch_bounds__(128) void local_scan1(
    const float* __restrict__ h1, const float* __restrict__ sc, const int* __restrict__ pm,
    float* __restrict__ PUl, float* __restrict__ PVl,
    float* __restrict__ dUl, float* __restrict__ dVl,
    float* __restrict__ cku, float* __restrict__ ckv,
    float* __restrict__ ckus, float* __restrict__ ckvs)
{
  const int head = blockIdx.x >> 6;
  const int chunk = blockIdx.x & 63;
  const int wave = threadIdx.x >> 6;
  const int lane = threadIdx.x & 63;
  const float cmax = sc[head * 4096 + 4095];
  const int base = head * 4096 + chunk * 64;
  const float cv = sc[base + lane];
  const float u = expf(cv - cmax);
  const float v = expf(0.2f * (cv - cmax));
  const int myj = pm[base + lane];
  const float* hrow = h1 + head * 64 + lane;
  if (wave == 0) {
    float iu = u, iv = v;
    #pragma unroll
    for (int o = 1; o < 64; o <<= 1) {
      const float tu = __shfl_up(iu, o), tv = __shfl_up(iv, o);
      if (lane >= o) { iu += tu; iv += tv; }
    }
    const float totU = __shfl(iu, 63), totV = __shfl(iv, 63);
    dVl[base + lane] = iv - v;
    dUl[base + lane] = totU - (iu - u);
    if (lane == 0) { ckus[head * 64 + chunk] = totU; ckvs[head * 64 + chunk] = totV; }
    float accV = 0.f;
    #pragma unroll 16
    for (int k = 0; k < 64; ++k) {
      const float vk = __shfl(v, k);
      const int j = __shfl(myj, k);
      PVl[(size_t)(base + k) * 64 + lane] = accV;
      accV += vk * hrow[(size_t)j * 256];
    }
    ckv[(head * 64 + chunk) * 64 + lane] = accV;
  } else {
    float accU = 0.f;
    #pragma unroll 16
    for (int k = 63; k >= 0; --k) {
      const float uk = __shfl(u, k);
      const int j = __shfl(myj, k);
      accU += uk * hrow[(size_t)j * 256];
      PUl[(size_t)(base + k) * 64 + lane] = accU;
    }
    cku[(head * 64 + chunk) * 64 + lane] = accU;
  }
}

// === local scan (GAT2, g=256): grid (colgrp=2, chunk=64); waves 0-1 PV, 2-3 PU ===
__global__ __launch_bounds__(256) void local_scan2(
    const float* __restrict__ h2, const float* __restrict__ sc, const int* __restrict__ pm,
    float* __restrict__ PUl, float* __restrict__ PVl,
    float* __restrict__ dUl, float* __restrict__ dVl,
    float* __restrict__ cku, float* __restrict__ ckv,
    float* __restrict__ ckus, float* __restrict__ ckvs)
{
  __shared__ float su[64], sv[64];
  __shared__ int sj[64];
  const int chunk = blockIdx.y;
  const int colgrp = blockIdx.x;
  const int tid = threadIdx.x;
  const int wave = tid >> 6, lane = tid & 63;
  const float cmax = sc[4095];
  const int base = chunk * 64;
  if (tid < 64) {
    const float cv = sc[base + tid];
    const float u = expf(cv - cmax);
    const float v = expf(0.2f * (cv - cmax));
    su[tid] = u; sv[tid] = v; sj[tid] = pm[base + tid];
    if (colgrp == 0) {
      float iu = u, iv = v;
      #pragma unroll
      for (int o = 1; o < 64; o <<= 1) {
        const float tu = __shfl_up(iu, o), tv = __shfl_up(iv, o);
        if (lane >= o) { iu += tu; iv += tv; }
      }
      const float totU = __shfl(iu, 63), totV = __shfl(iv, 63);
      dVl[base + lane] = iv - v;
      dUl[base + lane] = totU - (iu - u);
      if (lane == 0) { ckus[chunk] = totU; ckvs[chunk] = totV; }
    }
  }
  __syncthreads();
  const int col = colgrp * 128 + (wave & 1) * 64 + lane;
  if (wave < 2) {
    float accV = 0.f;
    #pragma unroll 16
    for (int k = 0; k < 64; ++k) {
      PVl[(size_t)(base + k) * 256 + col] = accV;
      accV += sv[k] * h2[(size_t)sj[k] * 256 + col];
    }
    ckv[chunk * 256 + col] = accV;
  } else {
    float accU = 0.f;
    #pragma unroll 16
    for (int k = 63; k >= 0; --k) {
      accU += su[k] * h2[(size_t)sj[k] * 256 + col];
      PUl[(size_t)(base + k) * 256 + col] = accU;
    }
    cku[chunk * 256 + col] = accU;
  }
}

// ======= chunk prefix/suffix: lane=col (coalesced), serial chunk loop =======
__global__ __launch_bounds__(64) void prefix1_kernel(
    const float* __restrict__ cku, const float* __restrict__ ckv,
    const float* __restrict__ ckus, const float* __restrict__ ckvs,
    float* __restrict__ sufU, float* __restrict__ prefV,
    float* __restrict__ sufUs, float* __restrict__ prefVs)
{
  const int head = blockIdx.x, lane = threadIdx.x;
  float acc = 0.f;
  for (int c = 0; c < 64; ++c) {
    prefV[(head * 65 + c) * 64 + lane] = acc;
    acc += ckv[(head * 64 + c) * 64 + lane];
  }
  prefV[(head * 65 + 64) * 64 + lane] = acc;
  acc = 0.f;
  sufU[(head * 65 + 64) * 64 + lane] = 0.f;
  for (int c = 63; c >= 0; --c) {
    acc += cku[(head * 64 + c) * 64 + lane];
    sufU[(head * 65 + c) * 64 + lane] = acc;
  }
  // scalars: contiguous -> wave scan over lane=chunk
  {
    const float vs = ckvs[head * 64 + lane];
    const float us = ckus[head * 64 + lane];
    float iv = vs, iu = us;
    #pragma unroll
    for (int o = 1; o < 64; o <<= 1) {
      const float tv = __shfl_up(iv, o), tu = __shfl_up(iu, o);
      if (lane >= o) { iv += tv; iu += tu; }
    }
    prefVs[head * 65 + lane] = iv - vs;
    const float totU = __shfl(iu, 63);
    sufUs[head * 65 + lane] = totU - iu + us;
    if (lane == 63) {
      prefVs[head * 65 + 64] = iv;
      sufUs[head * 65 + 64] = 0.f;
    }
  }
}

__global__ __launch_bounds__(256) void prefix2_kernel(
    const float* __restrict__ cku, const float* __restrict__ ckv,
    const float* __restrict__ ckus, const float* __restrict__ ckvs,
    float* __restrict__ sufU, float* __restrict__ prefV,
    float* __restrict__ sufUs, float* __restrict__ prefVs)
{
  const int col = threadIdx.x;
  const int lane = col & 63;
  float acc = 0.f;
  for (int c = 0; c < 64; ++c) {
    prefV[c * 256 + col] = acc;
    acc += ckv[c * 256 + col];
  }
  prefV[64 * 256 + col] = acc;
  acc = 0.f;
  sufU[64 * 256 + col] = 0.f;
  for (int c = 63; c >= 0; --c) {
    acc += cku[c * 256 + col];
    sufU[c * 256 + col] = acc;
  }
  if (col < 64) {
    const float vs = ckvs[lane];
    const float us = ckus[lane];
    float iv = vs, iu = us;
    #pragma unroll
    for (int o = 1; o < 64; o <<= 1) {
      const float tv = __shfl_up(iv, o), tu = __shfl_up(iu, o);
      if (lane >= o) { iv += tv; iu += tu; }
    }
    prefVs[lane] = iv - vs;
    const float totU = __shfl(iu, 63);
    sufUs[lane] = totU - iu + us;
    if (lane == 63) { prefVs[64] = iv; sufUs[64] = 0.f; }
  }
}

// ====== GAT1 combine: pure lookup. out = elu(att@h + b1) + minmax ======
__global__ __launch_bounds__(256) void combine1_kernel(
    const float* __restrict__ ci, const float* __restrict__ sc,
    const float* __restrict__ sufU, const float* __restrict__ prefV,
    const float* __restrict__ sufUs, const float* __restrict__ prefVs,
    const float* __restrict__ PUl, const float* __restrict__ PVl,
    const float* __restrict__ dUl, const float* __restrict__ dVl,
    const float* __restrict__ b1, float* __restrict__ out,
    float* __restrict__ pmn, float* __restrict__ pmx)
{
  const int i = blockIdx.x;
  const int head = threadIdx.x >> 6;
  const int lane = threadIdx.x & 63;
  const float* sch = sc + head * 4096;
  const float civ = ci[head * 4096 + i];
  const float cmax = sch[4095];
  const float sarg = civ + cmax;
  const float m = sarg > 0.f ? sarg : 0.2f * sarg;
  const float Af = expf(sarg - m);
  const float Bf = expf(0.2f * sarg - m);
  const float t = -civ;
  int lo = 0, hi = 4096;
  while (lo < hi) {
    const int mid = (lo + hi) >> 1;
    if (sch[mid] > t) hi = mid; else lo = mid + 1;
  }
  const int s = lo;
  float accP, accN, dP, dN;
  if (s == 4096) {
    accP = 0.f; dP = 0.f;
    accN = prefV[(head * 65 + 64) * 64 + lane];
    dN = prefVs[head * 65 + 64];
  } else {
    const int cs = s >> 6;
    accP = sufU[(head * 65 + cs + 1) * 64 + lane] + PUl[(size_t)(head * 4096 + s) * 64 + lane];
    accN = prefV[(head * 65 + cs) * 64 + lane] + PVl[(size_t)(head * 4096 + s) * 64 + lane];
    dP = sufUs[head * 65 + cs + 1] + dUl[head * 4096 + s];
    dN = prefVs[head * 65 + cs] + dVl[head * 4096 + s];
  }
  const float num = Af * accP + Bf * accN;
  const float den = Af * dP + Bf * dN;
  const float o = num / den + b1[head * 64 + lane];
  const float oe = o > 0.f ? o : expm1f(o);
  out[(size_t)i * 256 + head * 64 + lane] = oe;
  float mn = oe, mx = oe;
  #pragma unroll
  for (int of = 32; of > 0; of >>= 1) {
    mn = fminf(mn, __shfl_xor(mn, of));
    mx = fmaxf(mx, __shfl_xor(mx, of));
  }
  __shared__ float smn[4], smx[4];
  if (lane == 0) { smn[head] = mn; smx[head] = mx; }
  __syncthreads();
  if (threadIdx.x == 0) {
    pmn[i] = fminf(fminf(smn[0], smn[1]), fminf(smn[2], smn[3]));
    pmx[i] = fmaxf(fmaxf(smx[0], smx[1]), fmaxf(smx[2], smx[3]));
  }
}

// ========= GAT2 combine: pure lookup, writes bf16 =========
__global__ __launch_bounds__(256) void combine2_kernel(
    const float* __restrict__ ci, const float* __restrict__ sc,
    const float* __restrict__ sufU, const float* __restrict__ prefV,
    const float* __restrict__ sufUs, const float* __restrict__ prefVs,
    const float* __restrict__ PUl, const float* __restrict__ PVl,
    const float* __restrict__ dUl, const float* __restrict__ dVl,
    const float* __restrict__ b2, ushort* __restrict__ outb)
{
  const int i = blockIdx.x;
  const int col = threadIdx.x;
  const float civ = ci[i];
  const float cmax = sc[4095];
  const float sarg = civ + cmax;
  const float m = sarg > 0.f ? sarg : 0.2f * sarg;
  const float Af = expf(sarg - m);
  const float Bf = expf(0.2f * sarg - m);
  const float t = -civ;
  int lo = 0, hi = 4096;
  while (lo < hi) {
    const int mid = (lo + hi) >> 1;
    if (sc[mid] > t) hi = mid; else lo = mid + 1;
  }
  const int s = lo;
  float accP, accN, dP, dN;
  if (s == 4096) {
    accP = 0.f; dP = 0.f;
    accN = prefV[64 * 256 + col];
    dN = prefVs[64];
  } else {
    const int cs = s >> 6;
    accP = sufU[(cs + 1) * 256 + col] + PUl[(size_t)s * 256 + col];
    accN = prefV[cs * 256 + col] + PVl[(size_t)s * 256 + col];
    dP = sufUs[cs + 1] + dUl[s];
    dN = prefVs[cs] + dVl[s];
  }
  const float num = Af * accP + Bf * accN;
  const float den = Af * dP + Bf * dN;
  outb[(size_t)i * 256 + col] = f2b(num / den + b2[col]);
}

// ===== log-softmax + value extract; block 4096 = loss finalization =====
__global__ __launch_bounds__(64) void logsoftmax_kernel(
    const float* __restrict__ logits_ext, float* __restrict__ out,
    float* __restrict__ out_value,
    const float* __restrict__ p1, const float* __restrict__ p2,
    float* __restrict__ out_loss)
{
  const int i = blockIdx.x, lane = threadIdx.x;
  if (i == 4096) {
    float s = 0.f;
    #pragma unroll
    for (int k = 0; k < 4; ++k) s += p1[lane + k * 64] + p2[lane + k * 64];
    #pragma unroll
    for (int o = 32; o > 0; o >>= 1) s += __shfl_xor(s, o);
    if (lane == 0) out_loss[0] = s;
    return;
  }
  const float x = logits_ext[(size_t)i * 128 + lane];
  float mx = x;
  #pragma unroll
  for (int o = 32; o > 0; o >>= 1) mx = fmaxf(mx, __shfl_xor(mx, o));
  float e = expf(x - mx);
  #pragma unroll
  for (int o = 32; o > 0; o >>= 1) e += __shfl_xor(e, o);
  out[(size_t)i * 64 + lane] = x - mx - logf(e);
  if (lane == 0) out_value[i] = logits_ext[(size_t)i * 128 + 64];
}

// ============================ launch ============================
extern "C" void kernel_launch(void* const* d_in, const int* in_sizes, int n_in,
                              void* d_out, int out_size, void* d_ws, size_t ws_size,
                              hipStream_t stream) {
  const float* obs  = (const float*)d_in[0];
  const float* h0   = (const float*)d_in[1];
  const float* c0   = (const float*)d_in[2];
  const float* Wobs = (const float*)d_in[3];
  const float* bobs = (const float*)d_in[4];
  const float* Wih  = (const float*)d_in[5];
  const float* Whh  = (const float*)d_in[6];
  const float* bih  = (const float*)d_in[7];
  const float* bhh  = (const float*)d_in[8];
  const float* W1   = (const float*)d_in[9];
  const float* ai1  = (const float*)d_in[10];
  const float* aj1  = (const float*)d_in[11];
  const float* b1   = (const float*)d_in[12];
  const float* W2   = (const float*)d_in[13];
  const float* ai2  = (const float*)d_in[14];
  const float* aj2  = (const float*)d_in[15];
  const float* b2   = (const float*)d_in[16];
  const float* Wv   = (const float*)d_in[17];
  const float* bv   = (const float*)d_in[18];
  const float* Wa   = (const float*)d_in[19];
  const float* ba   = (const float*)d_in[20];

  float* out       = (float*)d_out;
  float* out_logp  = out;
  float* out_value = out + 262144;
  float* out_h     = out + 266240;
  float* out_c     = out + 1314816;
  float* out_loss  = out + 2363392;

  char* ws = (char*)d_ws;
  float* part1  = (float*)(ws + 256);
  float* part2  = (float*)(ws + 1280);
  float* pmn    = (float*)(ws + 2304);
  float* pmx    = (float*)(ws + 18688);
  const size_t MB = 1048576;
  const size_t base = 35072;
  ushort* obs_bf  = (ushort*)(ws + base);
  ushort* h0_bf   = (ushort*)(ws + base + 2 * MB);
  ushort* Wih_bf  = (ushort*)(ws + base + 4 * MB);
  ushort* Whh_bf  = (ushort*)(ws + base + 4 * MB + 524288);
  ushort* WobsT   = (ushort*)(ws + base + 5 * MB);
  ushort* W1T     = (ushort*)(ws + base + 5 * MB + 131072);
  ushort* W2T     = (ushort*)(ws + base + 5 * MB + 262144);
  ushort* WaTe    = (ushort*)(ws + base + 5 * MB + 393216);
  float*  bias_ext= (float*) (ws + base + 5 * MB + 524288);
  float*  bias12  = (float*) (ws + base + 5 * MB + 525312);
  ushort* enc_bf  = (ushort*)(ws + base + 6 * MB);
  ushort* h_bf    = (ushort*)(ws + base + 8 * MB);
  ushort* comm_q1 = (ushort*)(ws + base + 10 * MB);
  ushort* comm_q2 = (ushort*)(ws + base + 12 * MB);
  ushort* comm2_bf= (ushort*)(ws + base + 14 * MB);
  float*  gates   = (float*) (ws + base + 16 * MB);
  float*  h1      = gates;
  float*  comm1e  = (float*)((char*)gates + 4 * MB);
  float*  h2b     = (float*)((char*)gates + 8 * MB);
  float*  logits  = (float*)((char*)gates + 12 * MB);
  size_t so = base + 32 * MB;
  auto alloc = [&](size_t bytes) { size_t r = so; so += (bytes + 255) & ~255ull; return (char*)ws + r; };
  float* ci1    = (float*)alloc(4 * 4096 * 4);
  float* cj1    = (float*)alloc(4 * 4096 * 4);
  float* sc1    = (float*)alloc(4 * 4096 * 4);
  int*   pm1    = (int*)  alloc(4 * 4096 * 4);
  float* cku1   = (float*)alloc(4 * 64 * 64 * 4);
  float* ckv1   = (float*)alloc(4 * 64 * 64 * 4);
  float* ckus1  = (float*)alloc(4 * 64 * 4);
  float* ckvs1  = (float*)alloc(4 * 64 * 4);
  float* sufU1  = (float*)alloc(4 * 65 * 64 * 4);
  float* prefV1 = (float*)alloc(4 * 65 * 64 * 4);
  float* sufUs1 = (float*)alloc(4 * 65 * 4);
  float* prefVs1= (float*)alloc(4 * 65 * 4);
  float* ci2    = (float*)alloc(4096 * 4);
  float* cj2    = (float*)alloc(4096 * 4);
  float* sc2    = (float*)alloc(4096 * 4);
  int*   pm2    = (int*)  alloc(4096 * 4);
  float* cku2   = (float*)alloc(64 * 256 * 4);
  float* ckv2   = (float*)alloc(64 * 256 * 4);
  float* ckus2  = (float*)alloc(64 * 4);
  float* ckvs2  = (float*)alloc(64 * 4);
  float* sufU2  = (float*)alloc(65 * 256 * 4);
  float* prefV2 = (float*)alloc(65 * 256 * 4);
  float* sufUs2 = (float*)alloc(65 * 4);
  float* prefVs2= (float*)alloc(65 * 4);
  float* PUl    = (float*)alloc(4 * 4096 * 64 * 4);
  float* PVl    = (float*)alloc(4 * 4096 * 64 * 4);
  float* dUl    = (float*)alloc(4 * 4096 * 4);
  float* dVl    = (float*)alloc(4 * 4096 * 4);

  const dim3 b256(256);
  const int N4 = 262144;

  prep_kernel<<<dim3(1477), b256, 0, stream>>>(
      obs, obs_bf, h0, h0_bf, Wih, Wih_bf, Whh, Whh_bf,
      Wobs, WobsT, W1, W1T, W2, W2T,
      Wa, Wv, ba, bv, bih, bhh, WaTe, bias_ext, bias12);
  mfma_gemm<64, 64, true><<<dim3(4, 64), b256, 0, stream>>>(
      obs_bf, 256, WobsT, 256, 256, nullptr, 0, nullptr, 0, 0, bobs, enc_bf, 256);
  mfma_gemm<128, 128, false><<<dim3(8, 32), b256, 0, stream>>>(
      enc_bf, 256, Wih_bf, 256, 256, h0_bf, 256, Whh_bf, 256, 256, bias12, gates, 1024);
  lstm_elem_kernel<<<dim3(4096), b256, 0, stream>>>(gates, c0, out_h, out_c, h_bf, pmn, pmx);
  quant_kernel<<<dim3(256), b256, 0, stream>>>(
      (const float4*)out_h, comm_q1, N4, pmn, pmx, 4096, part1);
  // ---- GAT1 ----
  mfma_gemm<64, 64, false><<<dim3(4, 64), b256, 0, stream>>>(
      comm_q1, 256, W1T, 256, 256, nullptr, 0, nullptr, 0, 0, nullptr, h1, 256);
  cicj1_kernel<<<dim3(1024), b256, 0, stream>>>(h1, ai1, aj1, ci1, cj1);
  rank_sort_kernel<<<dim3(256), dim3(1024), 0, stream>>>(cj1, sc1, pm1);
  local_scan1<<<dim3(256), dim3(128), 0, stream>>>(h1, sc1, pm1,
      PUl, PVl, dUl, dVl, cku1, ckv1, ckus1, ckvs1);
  prefix1_kernel<<<dim3(4), dim3(64), 0, stream>>>(cku1, ckv1, ckus1, ckvs1,
                                                   sufU1, prefV1, sufUs1, prefVs1);
  combine1_kernel<<<dim3(4096), b256, 0, stream>>>(ci1, sc1,
      sufU1, prefV1, sufUs1, prefVs1, PUl, PVl, dUl, dVl, b1, comm1e, pmn, pmx);
  quant_kernel<<<dim3(256), b256, 0, stream>>>(
      (const float4*)comm1e, comm_q2, N4, pmn, pmx, 4096, part2);
  // ---- GAT2 ----
  mfma_gemm<64, 64, false><<<dim3(4, 64), b256, 0, stream>>>(
      comm_q2, 256, W2T, 256, 256, nullptr, 0, nullptr, 0, 0, nullptr, h2b, 256);
  cicj2_kernel<<<dim3(1024), b256, 0, stream>>>(h2b, ai2, aj2, ci2, cj2);
  rank_sort_kernel<<<dim3(64), dim3(1024), 0, stream>>>(cj2, sc2, pm2);
  local_scan2<<<dim3(2, 64), b256, 0, stream>>>(h2b, sc2, pm2,
      PUl, PVl, dUl, dVl, cku2, ckv2, ckus2, ckvs2);
  prefix2_kernel<<<dim3(1), b256, 0, stream>>>(cku2, ckv2, ckus2, ckvs2,
                                               sufU2, prefV2, sufUs2, prefVs2);
  combine2_kernel<<<dim3(4096), b256, 0, stream>>>(ci2, sc2,
      sufU2, prefV2, sufUs2, prefVs2, PUl, PVl, dUl, dVl, b2, comm2_bf);
  // ---- heads ----
  mfma_gemm<64, 64, false><<<dim3(2, 64), b256, 0, stream>>>(
      h_bf, 256, WaTe, 512, 256, comm2_bf, 256, WaTe + 256, 512, 256,
      bias_ext, logits, 128);
  logsoftmax_kernel<<<dim3(4097), dim3(64), 0, stream>>>(
      logits, out_logp, out_value, part1, part2, out_loss);
}

// Round 7
// 245.589 us; speedup vs baseline: 1.2378x; 1.0516x over previous
//
#include <hip/hip_runtime.h>
#include <math.h>

typedef __attribute__((ext_vector_type(8))) short short8;
typedef __attribute__((ext_vector_type(4))) float floatx4;

__device__ __forceinline__ ushort f2b(float f) {
  unsigned u = __float_as_uint(f);
  unsigned r = u + 0x7FFFu + ((u >> 16) & 1u);
  return (ushort)(r >> 16);
}

// ====== mega prep: convert obs/h0 + permuted Wih/Whh + transposes + misc ======
// Wih/Whh rows permuted: pr -> orow = (pr&3)*256 + (pr>>2), so gate quadruples
// of hidden unit d occupy output cols 4d..4d+3 (enables LSTM fusion in GEMM).
__global__ __launch_bounds__(256) void prep_kernel(
    const float* __restrict__ obs, ushort* __restrict__ obs_bf,
    const float* __restrict__ h0, ushort* __restrict__ h0_bf,
    const float* __restrict__ Wih, ushort* __restrict__ Wih_bf,
    const float* __restrict__ Whh, ushort* __restrict__ Whh_bf,
    const float* __restrict__ Wobs, ushort* __restrict__ WobsT,
    const float* __restrict__ W1, ushort* __restrict__ W1T,
    const float* __restrict__ W2, ushort* __restrict__ W2T,
    const float* __restrict__ Wa, const float* __restrict__ Wv,
    const float* __restrict__ ba, const float* __restrict__ bv,
    const float* __restrict__ bih, const float* __restrict__ bhh,
    ushort* __restrict__ WaTe, float* __restrict__ bias_ext, float* __restrict__ bias12)
{
  __shared__ float tile[32][33];
  const int bid = blockIdx.x;
  const int tid = threadIdx.x;
  if (bid < 1024) {
    const int q0 = 262144, q1 = 262144, q2 = 65536, q3 = 65536;
    const int tot = q0 + q1 + q2 + q3;
    for (int idx = bid * 256 + tid; idx < tot; idx += 1024 * 256) {
      const float* s; ushort* d; size_t soff, doff; int i = idx;
      if (i < q0) { s = obs; d = obs_bf; soff = doff = (size_t)i * 4; }
      else if ((i -= q0) < q1) { s = h0; d = h0_bf; soff = doff = (size_t)i * 4; }
      else if ((i -= q1) < q2) {
        const int pr = i >> 6, k4 = i & 63;
        const int orow = (pr & 3) * 256 + (pr >> 2);
        s = Wih; d = Wih_bf; soff = (size_t)orow * 256 + k4 * 4; doff = (size_t)pr * 256 + k4 * 4;
      } else {
        i -= q2;
        const int pr = i >> 6, k4 = i & 63;
        const int orow = (pr & 3) * 256 + (pr >> 2);
        s = Whh; d = Whh_bf; soff = (size_t)orow * 256 + k4 * 4; doff = (size_t)pr * 256 + k4 * 4;
      }
      const float4 v = *(const float4*)(s + soff);
      ushort4 o; o.x = f2b(v.x); o.y = f2b(v.y); o.z = f2b(v.z); o.w = f2b(v.w);
      *(ushort4*)(d + doff) = o;
    }
  } else if (bid < 1216) {
    const int t = bid - 1024;
    const int mat = t >> 6, sub = t & 63;
    const float* in = mat == 0 ? Wobs : (mat == 1 ? W1 : W2);
    ushort* outp = mat == 0 ? WobsT : (mat == 1 ? W1T : W2T);
    const int c0 = (sub & 7) * 32, r0 = (sub >> 3) * 32;
    const int tx = tid & 31, ty = tid >> 5;
    #pragma unroll
    for (int p = 0; p < 32; p += 8)
      tile[ty + p][tx] = in[(size_t)(r0 + ty + p) * 256 + c0 + tx];
    __syncthreads();
    #pragma unroll
    for (int p = 0; p < 32; p += 8)
      outp[(size_t)(c0 + ty + p) * 256 + r0 + tx] = f2b(tile[tx][ty + p]);
  } else {
    const int idx = (bid - 1216) * 256 + tid;
    if (idx < 65536) {
      const int n = idx >> 9, k = idx & 511;
      const float v = n < 64 ? Wa[(size_t)k * 64 + n] : (n == 64 ? Wv[k] : 0.0f);
      WaTe[idx] = f2b(v);
    } else if (idx < 65536 + 128) {
      const int n = idx - 65536;
      bias_ext[n] = n < 64 ? ba[n] : (n == 64 ? bv[0] : 0.0f);
    } else if (idx < 65536 + 128 + 1024) {
      const int pc = idx - 65536 - 128;
      const int orow = (pc & 3) * 256 + (pc >> 2);
      bias12[pc] = bih[orow] + bhh[orow];
    }
  }
}

// ===== MFMA GEMM: C[M,N] = A1@B1^T + A2@B2^T + bias (all NT, bf16 in) =====
template<int BM, int BN, bool OUT_BF16>
__global__ __launch_bounds__(256) void mfma_gemm(
    const ushort* __restrict__ A1, int lda1,
    const ushort* __restrict__ B1, int ldb1, int K1,
    const ushort* __restrict__ A2, int lda2,
    const ushort* __restrict__ B2, int ldb2, int K2,
    const float* __restrict__ bias,
    void* __restrict__ Cv, int N)
{
  constexpr int LDT = 40;
  __shared__ __align__(16) ushort As[BM * LDT];
  __shared__ __align__(16) ushort Bs[BN * LDT];
  const int tid = threadIdx.x;
  const int wave = tid >> 6, lane = tid & 63;
  const int wr = wave >> 1, wc = wave & 1;
  const int m0 = blockIdx.y * BM, n0 = blockIdx.x * BN;
  constexpr int MI = BM / 32;
  constexpr int NI = BN / 32;
  floatx4 acc[MI][NI] = {};
  const int r = tid >> 2, kq = tid & 3;
  const int lm = lane & 15, lq = lane >> 4;
  const int Ktot = K1 + K2;
  for (int k0 = 0; k0 < Ktot; k0 += 32) {
    const ushort* A; const ushort* B; int lda, ldb, kk;
    if (k0 < K1) { A = A1; B = B1; lda = lda1; ldb = ldb1; kk = k0; }
    else         { A = A2; B = B2; lda = lda2; ldb = ldb2; kk = k0 - K1; }
    #pragma unroll
    for (int p = 0; p < BM / 64; ++p) {
      const int rr = r + p * 64;
      *(float4*)&As[rr * LDT + kq * 8] =
          *(const float4*)&A[(size_t)(m0 + rr) * lda + kk + kq * 8];
    }
    #pragma unroll
    for (int p = 0; p < BN / 64; ++p) {
      const int rr = r + p * 64;
      *(float4*)&Bs[rr * LDT + kq * 8] =
          *(const float4*)&B[(size_t)(n0 + rr) * ldb + kk + kq * 8];
    }
    __syncthreads();
    short8 af[MI], bfr[NI];
    #pragma unroll
    for (int i = 0; i < MI; ++i)
      af[i] = *(const short8*)&As[(wr * (BM / 2) + i * 16 + lm) * LDT + lq * 8];
    #pragma unroll
    for (int j = 0; j < NI; ++j)
      bfr[j] = *(const short8*)&Bs[(wc * (BN / 2) + j * 16 + lm) * LDT + lq * 8];
    #pragma unroll
    for (int i = 0; i < MI; ++i)
      #pragma unroll
      for (int j = 0; j < NI; ++j)
        acc[i][j] = __builtin_amdgcn_mfma_f32_16x16x32_bf16(af[i], bfr[j], acc[i][j], 0, 0, 0);
    __syncthreads();
  }
  #pragma unroll
  for (int i = 0; i < MI; ++i) {
    #pragma unroll
    for (int j = 0; j < NI; ++j) {
      const int col = n0 + wc * (BN / 2) + j * 16 + lm;
      const float badd = bias ? bias[col] : 0.0f;
      #pragma unroll
      for (int t = 0; t < 4; ++t) {
        const int row = m0 + wr * (BM / 2) + i * 16 + lq * 4 + t;
        const float v = acc[i][j][t] + badd;
        if (OUT_BF16) ((ushort*)Cv)[(size_t)row * N + col] = f2b(v);
        else          ((float*)Cv)[(size_t)row * N + col] = v;
      }
    }
  }
}

// ===== fused gates GEMM (permuted cols) + LSTM + min/max partials =====
// grid (8, 32): n0 = bx*128 over 1024 permuted gate cols, m0 = by*128 rows.
__global__ __launch_bounds__(256) void gates_lstm_kernel(
    const ushort* __restrict__ enc_bf, const ushort* __restrict__ Wihp,
    const ushort* __restrict__ h0_bf, const ushort* __restrict__ Whhp,
    const float* __restrict__ bias12p, const float* __restrict__ c0,
    float* __restrict__ h_out, float* __restrict__ c_out, ushort* __restrict__ h_bf,
    float* __restrict__ pmn, float* __restrict__ pmx)
{
  constexpr int LDT = 40;
  __shared__ __align__(16) ushort As[128 * LDT];
  __shared__ __align__(16) ushort Bs[128 * LDT];
  __shared__ __align__(16) float gbuf[64][132];
  __shared__ float smn[4], smx[4];
  const int tid = threadIdx.x;
  const int wave = tid >> 6, lane = tid & 63;
  const int wr = wave >> 1, wc = wave & 1;
  const int m0 = blockIdx.y * 128, n0 = blockIdx.x * 128;
  floatx4 acc[4][4] = {};
  const int r = tid >> 2, kq = tid & 3;
  const int lm = lane & 15, lq = lane >> 4;
  for (int k0 = 0; k0 < 512; k0 += 32) {
    const ushort* A; const ushort* B; int kk;
    if (k0 < 256) { A = enc_bf; B = Wihp; kk = k0; }
    else          { A = h0_bf;  B = Whhp; kk = k0 - 256; }
    #pragma unroll
    for (int p = 0; p < 2; ++p) {
      const int rr = r + p * 64;
      *(float4*)&As[rr * LDT + kq * 8] =
          *(const float4*)&A[(size_t)(m0 + rr) * 256 + kk + kq * 8];
      *(float4*)&Bs[rr * LDT + kq * 8] =
          *(const float4*)&B[(size_t)(n0 + rr) * 256 + kk + kq * 8];
    }
    __syncthreads();
    short8 af[4], bfr[4];
    #pragma unroll
    for (int i = 0; i < 4; ++i)
      af[i] = *(const short8*)&As[(wr * 64 + i * 16 + lm) * LDT + lq * 8];
    #pragma unroll
    for (int j = 0; j < 4; ++j)
      bfr[j] = *(const short8*)&Bs[(wc * 64 + j * 16 + lm) * LDT + lq * 8];
    #pragma unroll
    for (int i = 0; i < 4; ++i)
      #pragma unroll
      for (int j = 0; j < 4; ++j)
        acc[i][j] = __builtin_amdgcn_mfma_f32_16x16x32_bf16(af[i], bfr[j], acc[i][j], 0, 0, 0);
    __syncthreads();
  }
  // epilogue: two 64-row halves through LDS, LSTM elementwise
  float mnl = 3.0e38f, mxl = -3.0e38f;
  const int rr = tid >> 2;            // 0..63
  const int dd0 = (tid & 3) * 8;      // 8 consecutive d per thread
  #pragma unroll
  for (int half = 0; half < 2; ++half) {
    if (wr == half) {
      #pragma unroll
      for (int i = 0; i < 4; ++i)
        #pragma unroll
        for (int j = 0; j < 4; ++j) {
          const int col = wc * 64 + j * 16 + lm;
          const float badd = bias12p[n0 + col];
          #pragma unroll
          for (int t = 0; t < 4; ++t)
            gbuf[i * 16 + lq * 4 + t][col] = acc[i][j][t] + badd;
        }
    }
    __syncthreads();
    const int ig = m0 + half * 64 + rr;
    #pragma unroll
    for (int eh = 0; eh < 2; ++eh) {
      const int ddb = dd0 + eh * 4;
      const size_t off = (size_t)ig * 256 + (n0 >> 2) + ddb;
      const float4 c4 = *(const float4*)&c0[off];
      float4 hv, cv; ushort4 hb;
      #pragma unroll
      for (int q = 0; q < 4; ++q) {
        const float4 g4 = *(const float4*)&gbuf[rr][(ddb + q) * 4];
        const float cc = ((const float*)&c4)[q];
        const float si = 1.0f / (1.0f + expf(-g4.x));
        const float sf = 1.0f / (1.0f + expf(-g4.y));
        const float so = 1.0f / (1.0f + expf(-g4.w));
        const float c2 = sf * cc + si * tanhf(g4.z);
        const float h2 = so * tanhf(c2);
        ((float*)&hv)[q] = h2; ((float*)&cv)[q] = c2; ((ushort*)&hb)[q] = f2b(h2);
        mnl = fminf(mnl, h2); mxl = fmaxf(mxl, h2);
      }
      *(float4*)&h_out[off] = hv;
      *(float4*)&c_out[off] = cv;
      *(ushort4*)&h_bf[off] = hb;
    }
    __syncthreads();
  }
  #pragma unroll
  for (int o = 32; o > 0; o >>= 1) {
    mnl = fminf(mnl, __shfl_xor(mnl, o));
    mxl = fmaxf(mxl, __shfl_xor(mxl, o));
  }
  if (lane == 0) { smn[wave] = mnl; smx[wave] = mxl; }
  __syncthreads();
  if (tid == 0) {
    const int bid = blockIdx.y * 8 + blockIdx.x;
    pmn[bid] = fminf(fminf(smn[0], smn[1]), fminf(smn[2], smn[3]));
    pmx[bid] = fmaxf(fmaxf(smx[0], smx[1]), fmaxf(smx[2], smx[3]));
  }
}

// === fake-quant (fused global min/max from partials) -> bf16 + loss partial ===
__global__ __launch_bounds__(256) void quant_kernel(
    const float4* __restrict__ x, ushort* __restrict__ q, int n4,
    const float* __restrict__ pmn, const float* __restrict__ pmx, int np,
    float* __restrict__ part)
{
  __shared__ float smn[4], smx[4], sl[4], bmn, bmx;
  float mn = 3.0e38f, mx = -3.0e38f;
  for (int i = threadIdx.x; i < np; i += 256) {
    mn = fminf(mn, pmn[i]); mx = fmaxf(mx, pmx[i]);
  }
  #pragma unroll
  for (int o = 32; o > 0; o >>= 1) {
    mn = fminf(mn, __shfl_xor(mn, o));
    mx = fmaxf(mx, __shfl_xor(mx, o));
  }
  if ((threadIdx.x & 63) == 0) { smn[threadIdx.x >> 6] = mn; smx[threadIdx.x >> 6] = mx; }
  __syncthreads();
  if (threadIdx.x == 0) {
    bmn = fminf(fminf(smn[0], smn[1]), fminf(smn[2], smn[3]));
    bmx = fmaxf(fmaxf(smx[0], smx[1]), fmaxf(smx[2], smx[3]));
  }
  __syncthreads();
  mn = bmn; mx = bmx;
  if (mn == mx) { mn -= 0.01f; mx += 0.01f; }
  const float scale = (mx - mn) / 255.0f;
  const float zp = rintf(-mn / scale);
  float lsum = 0.0f;
  for (int idx = blockIdx.x * 256 + threadIdx.x; idx < n4; idx += gridDim.x * 256) {
    const float4 t = x[idx];
    float d0, d1, d2, d3;
    { float qq = fminf(fmaxf(rintf(t.x / scale + zp), 0.0f), 255.0f);
      d0 = (qq - zp) * scale; lsum += log2f(510.0f * fabsf(d0) + 1.0f); }
    { float qq = fminf(fmaxf(rintf(t.y / scale + zp), 0.0f), 255.0f);
      d1 = (qq - zp) * scale; lsum += log2f(510.0f * fabsf(d1) + 1.0f); }
    { float qq = fminf(fmaxf(rintf(t.z / scale + zp), 0.0f), 255.0f);
      d2 = (qq - zp) * scale; lsum += log2f(510.0f * fabsf(d2) + 1.0f); }
    { float qq = fminf(fmaxf(rintf(t.w / scale + zp), 0.0f), 255.0f);
      d3 = (qq - zp) * scale; lsum += log2f(510.0f * fabsf(d3) + 1.0f); }
    ushort4 o; o.x = f2b(d0); o.y = f2b(d1); o.z = f2b(d2); o.w = f2b(d3);
    *(ushort4*)(q + (size_t)idx * 4) = o;
  }
  #pragma unroll
  for (int o = 32; o > 0; o >>= 1) lsum += __shfl_xor(lsum, o);
  if ((threadIdx.x & 63) == 0) sl[threadIdx.x >> 6] = lsum;
  __syncthreads();
  if (threadIdx.x == 0) part[blockIdx.x] = sl[0] + sl[1] + sl[2] + sl[3];
}

// ==================== GAT attention coefficients ====================
__global__ __launch_bounds__(256) void cicj1_kernel(
    const float* __restrict__ h1, const float* __restrict__ ai, const float* __restrict__ aj,
    float* __restrict__ ci, float* __restrict__ cj)
{
  const int w = threadIdx.x >> 6, lane = threadIdx.x & 63;
  const int i = blockIdx.x * 4 + w;
  #pragma unroll
  for (int hd = 0; hd < 4; ++hd) {
    const float v = h1[(size_t)i * 256 + hd * 64 + lane];
    float pi = v * ai[hd * 64 + lane];
    float pj = v * aj[hd * 64 + lane];
    #pragma unroll
    for (int o = 32; o > 0; o >>= 1) { pi += __shfl_xor(pi, o); pj += __shfl_xor(pj, o); }
    if (lane == 0) { ci[hd * 4096 + i] = pi; cj[hd * 4096 + i] = pj; }
  }
}

__global__ __launch_bounds__(256) void cicj2_kernel(
    const float* __restrict__ h2, const float* __restrict__ ai, const float* __restrict__ aj,
    float* __restrict__ ci, float* __restrict__ cj)
{
  const int w = threadIdx.x >> 6, lane = threadIdx.x & 63;
  const int i = blockIdx.x * 4 + w;
  float pi = 0.f, pj = 0.f;
  #pragma unroll
  for (int r = 0; r < 4; ++r) {
    const float v = h2[(size_t)i * 256 + r * 64 + lane];
    pi += v * ai[r * 64 + lane];
    pj += v * aj[r * 64 + lane];
  }
  #pragma unroll
  for (int o = 32; o > 0; o >>= 1) { pi += __shfl_xor(pi, o); pj += __shfl_xor(pj, o); }
  if (lane == 0) { ci[i] = pi; cj[i] = pj; }
}

// ====== rank sort via u64 keys (enc(float)<<12 | idx): 1 cmp per key ======
__global__ __launch_bounds__(1024) void rank_sort_kernel(
    const float* __restrict__ c, float* __restrict__ sc, int* __restrict__ pm)
{
  __shared__ unsigned long long lk[4096];
  __shared__ int scnt[16][64];
  const int head = blockIdx.x >> 6;
  const int seg = blockIdx.x & 63;
  const float* ch = c + head * 4096;
  for (int idx = threadIdx.x; idx < 4096; idx += 1024) {
    unsigned u = __float_as_uint(ch[idx]);
    u = (u & 0x80000000u) ? ~u : (u | 0x80000000u);
    lk[idx] = ((unsigned long long)u << 12) | (unsigned)idx;
  }
  __syncthreads();
  const int jl = threadIdx.x & 63;
  const int kg = threadIdx.x >> 6;
  const unsigned long long my = lk[seg * 64 + jl];
  int cnt = 0;
  const int k0 = kg * 256;
  #pragma unroll 8
  for (int k = k0; k < k0 + 256; ++k)
    cnt += lk[k] < my ? 1 : 0;
  scnt[kg][jl] = cnt;
  __syncthreads();
  if (threadIdx.x < 64) {
    int rank = 0;
    #pragma unroll
    for (int g = 0; g < 16; ++g) rank += scnt[g][threadIdx.x];
    const unsigned long long kk = lk[seg * 64 + threadIdx.x];
    unsigned u = (unsigned)(kk >> 12);
    const float v = __uint_as_float((u & 0x80000000u) ? (u & 0x7fffffffu) : ~u);
    sc[head * 4096 + rank] = v;
    pm[head * 4096 + rank] = (int)(kk & 0xFFFu);
  }
}

// ======= local scan (GAT1): 2 waves/block, wave0=PV asc, wave1=PU desc =======
__global__ __launch_bounds__(128) void local_scan1(
    const float* __restrict__ h1, const float* __restrict__ sc, const int* __restrict__ pm,
    float* __restrict__ PUl, float* __restrict__ PVl,
    float* __restrict__ dUl, float* __restrict__ dVl,
    float* __restrict__ cku, float* __restrict__ ckv,
    float* __restrict__ ckus, float* __restrict__ ckvs)
{
  const int head = blockIdx.x >> 6;
  const int chunk = blockIdx.x & 63;
  const int wave = threadIdx.x >> 6;
  const int lane = threadIdx.x & 63;
  const float cmax = sc[head * 4096 + 4095];
  const int base = head * 4096 + chunk * 64;
  const float cv = sc[base + lane];
  const float u = expf(cv - cmax);
  const float v = expf(0.2f * (cv - cmax));
  const int myj = pm[base + lane];
  const float* hrow = h1 + head * 64 + lane;
  if (wave == 0) {
    float iu = u, iv = v;
    #pragma unroll
    for (int o = 1; o < 64; o <<= 1) {
      const float tu = __shfl_up(iu, o), tv = __shfl_up(iv, o);
      if (lane >= o) { iu += tu; iv += tv; }
    }
    const float totU = __shfl(iu, 63), totV = __shfl(iv, 63);
    dVl[base + lane] = iv - v;
    dUl[base + lane] = totU - (iu - u);
    if (lane == 0) { ckus[head * 64 + chunk] = totU; ckvs[head * 64 + chunk] = totV; }
    float accV = 0.f;
    #pragma unroll 16
    for (int k = 0; k < 64; ++k) {
      const float vk = __shfl(v, k);
      const int j = __shfl(myj, k);
      PVl[(size_t)(base + k) * 64 + lane] = accV;
      accV += vk * hrow[(size_t)j * 256];
    }
    ckv[(head * 64 + chunk) * 64 + lane] = accV;
  } else {
    float accU = 0.f;
    #pragma unroll 16
    for (int k = 63; k >= 0; --k) {
      const float uk = __shfl(u, k);
      const int j = __shfl(myj, k);
      accU += uk * hrow[(size_t)j * 256];
      PUl[(size_t)(base + k) * 64 + lane] = accU;
    }
    cku[(head * 64 + chunk) * 64 + lane] = accU;
  }
}

// === local scan (GAT2, g=256): grid (colgrp=2, chunk=64); waves 0-1 PV, 2-3 PU ===
__global__ __launch_bounds__(256) void local_scan2(
    const float* __restrict__ h2, const float* __restrict__ sc, const int* __restrict__ pm,
    float* __restrict__ PUl, float* __restrict__ PVl,
    float* __restrict__ dUl, float* __restrict__ dVl,
    float* __restrict__ cku, float* __restrict__ ckv,
    float* __restrict__ ckus, float* __restrict__ ckvs)
{
  __shared__ float su[64], sv[64];
  __shared__ int sj[64];
  const int chunk = blockIdx.y;
  const int colgrp = blockIdx.x;
  const int tid = threadIdx.x;
  const int wave = tid >> 6, lane = tid & 63;
  const float cmax = sc[4095];
  const int base = chunk * 64;
  if (tid < 64) {
    const float cv = sc[base + tid];
    const float u = expf(cv - cmax);
    const float v = expf(0.2f * (cv - cmax));
    su[tid] = u; sv[tid] = v; sj[tid] = pm[base + tid];
    if (colgrp == 0) {
      float iu = u, iv = v;
      #pragma unroll
      for (int o = 1; o < 64; o <<= 1) {
        const float tu = __shfl_up(iu, o), tv = __shfl_up(iv, o);
        if (lane >= o) { iu += tu; iv += tv; }
      }
      const float totU = __shfl(iu, 63), totV = __shfl(iv, 63);
      dVl[base + lane] = iv - v;
      dUl[base + lane] = totU - (iu - u);
      if (lane == 0) { ckus[chunk] = totU; ckvs[chunk] = totV; }
    }
  }
  __syncthreads();
  const int col = colgrp * 128 + (wave & 1) * 64 + lane;
  if (wave < 2) {
    float accV = 0.f;
    #pragma unroll 16
    for (int k = 0; k < 64; ++k) {
      PVl[(size_t)(base + k) * 256 + col] = accV;
      accV += sv[k] * h2[(size_t)sj[k] * 256 + col];
    }
    ckv[chunk * 256 + col] = accV;
  } else {
    float accU = 0.f;
    #pragma unroll 16
    for (int k = 63; k >= 0; --k) {
      accU += su[k] * h2[(size_t)sj[k] * 256 + col];
      PUl[(size_t)(base + k) * 256 + col] = accU;
    }
    cku[chunk * 256 + col] = accU;
  }
}

// ======= chunk prefix/suffix: lane=col (coalesced), serial chunk loop =======
__global__ __launch_bounds__(64) void prefix1_kernel(
    const float* __restrict__ cku, const float* __restrict__ ckv,
    const float* __restrict__ ckus, const float* __restrict__ ckvs,
    float* __restrict__ sufU, float* __restrict__ prefV,
    float* __restrict__ sufUs, float* __restrict__ prefVs)
{
  const int head = blockIdx.x, lane = threadIdx.x;
  float acc = 0.f;
  for (int c = 0; c < 64; ++c) {
    prefV[(head * 65 + c) * 64 + lane] = acc;
    acc += ckv[(head * 64 + c) * 64 + lane];
  }
  prefV[(head * 65 + 64) * 64 + lane] = acc;
  acc = 0.f;
  sufU[(head * 65 + 64) * 64 + lane] = 0.f;
  for (int c = 63; c >= 0; --c) {
    acc += cku[(head * 64 + c) * 64 + lane];
    sufU[(head * 65 + c) * 64 + lane] = acc;
  }
  {
    const float vs = ckvs[head * 64 + lane];
    const float us = ckus[head * 64 + lane];
    float iv = vs, iu = us;
    #pragma unroll
    for (int o = 1; o < 64; o <<= 1) {
      const float tv = __shfl_up(iv, o), tu = __shfl_up(iu, o);
      if (lane >= o) { iv += tv; iu += tu; }
    }
    prefVs[head * 65 + lane] = iv - vs;
    const float totU = __shfl(iu, 63);
    sufUs[head * 65 + lane] = totU - iu + us;
    if (lane == 63) {
      prefVs[head * 65 + 64] = iv;
      sufUs[head * 65 + 64] = 0.f;
    }
  }
}

__global__ __launch_bounds__(256) void prefix2_kernel(
    const float* __restrict__ cku, const float* __restrict__ ckv,
    const float* __restrict__ ckus, const float* __restrict__ ckvs,
    float* __restrict__ sufU, float* __restrict__ prefV,
    float* __restrict__ sufUs, float* __restrict__ prefVs)
{
  const int col = threadIdx.x;
  const int lane = col & 63;
  float acc = 0.f;
  for (int c = 0; c < 64; ++c) {
    prefV[c * 256 + col] = acc;
    acc += ckv[c * 256 + col];
  }
  prefV[64 * 256 + col] = acc;
  acc = 0.f;
  sufU[64 * 256 + col] = 0.f;
  for (int c = 63; c >= 0; --c) {
    acc += cku[c * 256 + col];
    sufU[c * 256 + col] = acc;
  }
  if (col < 64) {
    const float vs = ckvs[lane];
    const float us = ckus[lane];
    float iv = vs, iu = us;
    #pragma unroll
    for (int o = 1; o < 64; o <<= 1) {
      const float tv = __shfl_up(iv, o), tu = __shfl_up(iu, o);
      if (lane >= o) { iv += tv; iu += tu; }
    }
    prefVs[lane] = iv - vs;
    const float totU = __shfl(iu, 63);
    sufUs[lane] = totU - iu + us;
    if (lane == 63) { prefVs[64] = iv; sufUs[64] = 0.f; }
  }
}

// ====== GAT1 combine: pure lookup. out = elu(att@h + b1) + minmax ======
__global__ __launch_bounds__(256) void combine1_kernel(
    const float* __restrict__ ci, const float* __restrict__ sc,
    const float* __restrict__ sufU, const float* __restrict__ prefV,
    const float* __restrict__ sufUs, const float* __restrict__ prefVs,
    const float* __restrict__ PUl, const float* __restrict__ PVl,
    const float* __restrict__ dUl, const float* __restrict__ dVl,
    const float* __restrict__ b1, float* __restrict__ out,
    float* __restrict__ pmn, float* __restrict__ pmx)
{
  const int i = blockIdx.x;
  const int head = threadIdx.x >> 6;
  const int lane = threadIdx.x & 63;
  const float* sch = sc + head * 4096;
  const float civ = ci[head * 4096 + i];
  const float cmax = sch[4095];
  const float sarg = civ + cmax;
  const float m = sarg > 0.f ? sarg : 0.2f * sarg;
  const float Af = expf(sarg - m);
  const float Bf = expf(0.2f * sarg - m);
  const float t = -civ;
  int lo = 0, hi = 4096;
  while (lo < hi) {
    const int mid = (lo + hi) >> 1;
    if (sch[mid] > t) hi = mid; else lo = mid + 1;
  }
  const int s = lo;
  float accP, accN, dP, dN;
  if (s == 4096) {
    accP = 0.f; dP = 0.f;
    accN = prefV[(head * 65 + 64) * 64 + lane];
    dN = prefVs[head * 65 + 64];
  } else {
    const int cs = s >> 6;
    accP = sufU[(head * 65 + cs + 1) * 64 + lane] + PUl[(size_t)(head * 4096 + s) * 64 + lane];
    accN = prefV[(head * 65 + cs) * 64 + lane] + PVl[(size_t)(head * 4096 + s) * 64 + lane];
    dP = sufUs[head * 65 + cs + 1] + dUl[head * 4096 + s];
    dN = prefVs[head * 65 + cs] + dVl[head * 4096 + s];
  }
  const float num = Af * accP + Bf * accN;
  const float den = Af * dP + Bf * dN;
  const float o = num / den + b1[head * 64 + lane];
  const float oe = o > 0.f ? o : expm1f(o);
  out[(size_t)i * 256 + head * 64 + lane] = oe;
  float mn = oe, mx = oe;
  #pragma unroll
  for (int of = 32; of > 0; of >>= 1) {
    mn = fminf(mn, __shfl_xor(mn, of));
    mx = fmaxf(mx, __shfl_xor(mx, of));
  }
  __shared__ float smn[4], smx[4];
  if (lane == 0) { smn[head] = mn; smx[head] = mx; }
  __syncthreads();
  if (threadIdx.x == 0) {
    pmn[i] = fminf(fminf(smn[0], smn[1]), fminf(smn[2], smn[3]));
    pmx[i] = fmaxf(fmaxf(smx[0], smx[1]), fmaxf(smx[2], smx[3]));
  }
}

// ========= GAT2 combine: pure lookup, writes bf16 =========
__global__ __launch_bounds__(256) void combine2_kernel(
    const float* __restrict__ ci, const float* __restrict__ sc,
    const float* __restrict__ sufU, const float* __restrict__ prefV,
    const float* __restrict__ sufUs, const float* __restrict__ prefVs,
    const float* __restrict__ PUl, const float* __restrict__ PVl,
    const float* __restrict__ dUl, const float* __restrict__ dVl,
    const float* __restrict__ b2, ushort* __restrict__ outb)
{
  const int i = blockIdx.x;
  const int col = threadIdx.x;
  const float civ = ci[i];
  const float cmax = sc[4095];
  const float sarg = civ + cmax;
  const float m = sarg > 0.f ? sarg : 0.2f * sarg;
  const float Af = expf(sarg - m);
  const float Bf = expf(0.2f * sarg - m);
  const float t = -civ;
  int lo = 0, hi = 4096;
  while (lo < hi) {
    const int mid = (lo + hi) >> 1;
    if (sc[mid] > t) hi = mid; else lo = mid + 1;
  }
  const int s = lo;
  float accP, accN, dP, dN;
  if (s == 4096) {
    accP = 0.f; dP = 0.f;
    accN = prefV[64 * 256 + col];
    dN = prefVs[64];
  } else {
    const int cs = s >> 6;
    accP = sufU[(cs + 1) * 256 + col] + PUl[(size_t)s * 256 + col];
    accN = prefV[cs * 256 + col] + PVl[(size_t)s * 256 + col];
    dP = sufUs[cs + 1] + dUl[s];
    dN = prefVs[cs] + dVl[s];
  }
  const float num = Af * accP + Bf * accN;
  const float den = Af * dP + Bf * dN;
  outb[(size_t)i * 256 + col] = f2b(num / den + b2[col]);
}

// ==== heads: [h|comm2]@WaTe^T + bias, fused log-softmax + value + loss ====
// grid 64 blocks x 256 thr; BM=64 rows, N=128 cols (col 64 = value head).
__global__ __launch_bounds__(256) void heads_kernel(
    const ushort* __restrict__ h_bf, const ushort* __restrict__ comm2_bf,
    const ushort* __restrict__ WaTe, const float* __restrict__ bias_ext,
    float* __restrict__ out_logp, float* __restrict__ out_value,
    const float* __restrict__ p1, const float* __restrict__ p2,
    float* __restrict__ out_loss)
{
  constexpr int LDT = 40;
  __shared__ __align__(16) ushort As[64 * LDT];
  __shared__ __align__(16) ushort Bs[128 * LDT];
  __shared__ float lbuf[64][68];
  const int tid = threadIdx.x;
  const int wave = tid >> 6, lane = tid & 63;
  const int wr = wave >> 1, wc = wave & 1;
  const int m0 = blockIdx.x * 64;
  const int lm = lane & 15, lq = lane >> 4;
  floatx4 acc[2][4] = {};
  const int r = tid >> 2, kq = tid & 3;
  for (int k0 = 0; k0 < 512; k0 += 32) {
    const ushort* Asrc = (k0 < 256) ? h_bf : comm2_bf;
    const int kk = (k0 < 256) ? k0 : k0 - 256;
    *(float4*)&As[r * LDT + kq * 8] =
        *(const float4*)&Asrc[(size_t)(m0 + r) * 256 + kk + kq * 8];
    #pragma unroll
    for (int p = 0; p < 2; ++p) {
      const int rr = r + p * 64;
      *(float4*)&Bs[rr * LDT + kq * 8] =
          *(const float4*)&WaTe[(size_t)rr * 512 + k0 + kq * 8];
    }
    __syncthreads();
    short8 af[2], bfr[4];
    #pragma unroll
    for (int i = 0; i < 2; ++i)
      af[i] = *(const short8*)&As[(wr * 32 + i * 16 + lm) * LDT + lq * 8];
    #pragma unroll
    for (int j = 0; j < 4; ++j)
      bfr[j] = *(const short8*)&Bs[(wc * 64 + j * 16 + lm) * LDT + lq * 8];
    #pragma unroll
    for (int i = 0; i < 2; ++i)
      #pragma unroll
      for (int j = 0; j < 4; ++j)
        acc[i][j] = __builtin_amdgcn_mfma_f32_16x16x32_bf16(af[i], bfr[j], acc[i][j], 0, 0, 0);
    __syncthreads();
  }
  #pragma unroll
  for (int i = 0; i < 2; ++i)
    #pragma unroll
    for (int j = 0; j < 4; ++j) {
      const int col = wc * 64 + j * 16 + lm;
      if (col < 65) {
        const float badd = bias_ext[col];
        #pragma unroll
        for (int t = 0; t < 4; ++t)
          lbuf[wr * 32 + i * 16 + lq * 4 + t][col] = acc[i][j][t] + badd;
      }
    }
  __syncthreads();
  for (int rr2 = 0; rr2 < 16; ++rr2) {
    const int row = wave * 16 + rr2;
    const float x = lbuf[row][lane];
    float mx = x;
    #pragma unroll
    for (int o = 32; o > 0; o >>= 1) mx = fmaxf(mx, __shfl_xor(mx, o));
    float e = expf(x - mx);
    #pragma unroll
    for (int o = 32; o > 0; o >>= 1) e += __shfl_xor(e, o);
    out_logp[(size_t)(m0 + row) * 64 + lane] = x - mx - logf(e);
    if (lane == 0) out_value[m0 + row] = lbuf[row][64];
  }
  if (blockIdx.x == 0 && wave == 0) {
    float s = 0.f;
    #pragma unroll
    for (int k = 0; k < 4; ++k) s += p1[lane + k * 64] + p2[lane + k * 64];
    #pragma unroll
    for (int o = 32; o > 0; o >>= 1) s += __shfl_xor(s, o);
    if (lane == 0) out_loss[0] = s;
  }
}

// ============================ launch ============================
extern "C" void kernel_launch(void* const* d_in, const int* in_sizes, int n_in,
                              void* d_out, int out_size, void* d_ws, size_t ws_size,
                              hipStream_t stream) {
  const float* obs  = (const float*)d_in[0];
  const float* h0   = (const float*)d_in[1];
  const float* c0   = (const float*)d_in[2];
  const float* Wobs = (const float*)d_in[3];
  const float* bobs = (const float*)d_in[4];
  const float* Wih  = (const float*)d_in[5];
  const float* Whh  = (const float*)d_in[6];
  const float* bih  = (const float*)d_in[7];
  const float* bhh  = (const float*)d_in[8];
  const float* W1   = (const float*)d_in[9];
  const float* ai1  = (const float*)d_in[10];
  const float* aj1  = (const float*)d_in[11];
  const float* b1   = (const float*)d_in[12];
  const float* W2   = (const float*)d_in[13];
  const float* ai2  = (const float*)d_in[14];
  const float* aj2  = (const float*)d_in[15];
  const float* b2   = (const float*)d_in[16];
  const float* Wv   = (const float*)d_in[17];
  const float* bv   = (const float*)d_in[18];
  const float* Wa   = (const float*)d_in[19];
  const float* ba   = (const float*)d_in[20];

  float* out       = (float*)d_out;
  float* out_logp  = out;
  float* out_value = out + 262144;
  float* out_h     = out + 266240;
  float* out_c     = out + 1314816;
  float* out_loss  = out + 2363392;

  char* ws = (char*)d_ws;
  float* part1  = (float*)(ws + 256);
  float* part2  = (float*)(ws + 1280);
  float* pmn    = (float*)(ws + 2304);
  float* pmx    = (float*)(ws + 18688);
  const size_t MB = 1048576;
  const size_t base = 35072;
  ushort* obs_bf  = (ushort*)(ws + base);
  ushort* h0_bf   = (ushort*)(ws + base + 2 * MB);
  ushort* Wih_bf  = (ushort*)(ws + base + 4 * MB);
  ushort* Whh_bf  = (ushort*)(ws + base + 4 * MB + 524288);
  ushort* WobsT   = (ushort*)(ws + base + 5 * MB);
  ushort* W1T     = (ushort*)(ws + base + 5 * MB + 131072);
  ushort* W2T     = (ushort*)(ws + base + 5 * MB + 262144);
  ushort* WaTe    = (ushort*)(ws + base + 5 * MB + 393216);
  float*  bias_ext= (float*) (ws + base + 5 * MB + 524288);
  float*  bias12  = (float*) (ws + base + 5 * MB + 525312);
  ushort* enc_bf  = (ushort*)(ws + base + 6 * MB);
  ushort* h_bf    = (ushort*)(ws + base + 8 * MB);
  ushort* comm_q1 = (ushort*)(ws + base + 10 * MB);
  ushort* comm_q2 = (ushort*)(ws + base + 12 * MB);
  ushort* comm2_bf= (ushort*)(ws + base + 14 * MB);
  float*  scratch = (float*) (ws + base + 16 * MB);   // 16 MB region
  float*  h1      = scratch;
  float*  comm1e  = (float*)((char*)scratch + 4 * MB);
  float*  h2b     = (float*)((char*)scratch + 8 * MB);
  size_t so = base + 32 * MB;
  auto alloc = [&](size_t bytes) { size_t r = so; so += (bytes + 255) & ~255ull; return (char*)ws + r; };
  float* ci1    = (float*)alloc(4 * 4096 * 4);
  float* cj1    = (float*)alloc(4 * 4096 * 4);
  float* sc1    = (float*)alloc(4 * 4096 * 4);
  int*   pm1    = (int*)  alloc(4 * 4096 * 4);
  float* cku1   = (float*)alloc(4 * 64 * 64 * 4);
  float* ckv1   = (float*)alloc(4 * 64 * 64 * 4);
  float* ckus1  = (float*)alloc(4 * 64 * 4);
  float* ckvs1  = (float*)alloc(4 * 64 * 4);
  float* sufU1  = (float*)alloc(4 * 65 * 64 * 4);
  float* prefV1 = (float*)alloc(4 * 65 * 64 * 4);
  float* sufUs1 = (float*)alloc(4 * 65 * 4);
  float* prefVs1= (float*)alloc(4 * 65 * 4);
  float* ci2    = (float*)alloc(4096 * 4);
  float* cj2    = (float*)alloc(4096 * 4);
  float* sc2    = (float*)alloc(4096 * 4);
  int*   pm2    = (int*)  alloc(4096 * 4);
  float* cku2   = (float*)alloc(64 * 256 * 4);
  float* ckv2   = (float*)alloc(64 * 256 * 4);
  float* ckus2  = (float*)alloc(64 * 4);
  float* ckvs2  = (float*)alloc(64 * 4);
  float* sufU2  = (float*)alloc(65 * 256 * 4);
  float* prefV2 = (float*)alloc(65 * 256 * 4);
  float* sufUs2 = (float*)alloc(65 * 4);
  float* prefVs2= (float*)alloc(65 * 4);
  float* PUl    = (float*)alloc(4 * 4096 * 64 * 4);
  float* PVl    = (float*)alloc(4 * 4096 * 64 * 4);
  float* dUl    = (float*)alloc(4 * 4096 * 4);
  float* dVl    = (float*)alloc(4 * 4096 * 4);

  const dim3 b256(256);
  const int N4 = 262144;

  prep_kernel<<<dim3(1477), b256, 0, stream>>>(
      obs, obs_bf, h0, h0_bf, Wih, Wih_bf, Whh, Whh_bf,
      Wobs, WobsT, W1, W1T, W2, W2T,
      Wa, Wv, ba, bv, bih, bhh, WaTe, bias_ext, bias12);
  mfma_gemm<64, 64, true><<<dim3(4, 64), b256, 0, stream>>>(
      obs_bf, 256, WobsT, 256, 256, nullptr, 0, nullptr, 0, 0, bobs, enc_bf, 256);
  gates_lstm_kernel<<<dim3(8, 32), b256, 0, stream>>>(
      enc_bf, Wih_bf, h0_bf, Whh_bf, bias12, c0, out_h, out_c, h_bf, pmn, pmx);
  quant_kernel<<<dim3(256), b256, 0, stream>>>(
      (const float4*)out_h, comm_q1, N4, pmn, pmx, 256, part1);
  // ---- GAT1 ----
  mfma_gemm<64, 64, false><<<dim3(4, 64), b256, 0, stream>>>(
      comm_q1, 256, W1T, 256, 256, nullptr, 0, nullptr, 0, 0, nullptr, h1, 256);
  cicj1_kernel<<<dim3(1024), b256, 0, stream>>>(h1, ai1, aj1, ci1, cj1);
  rank_sort_kernel<<<dim3(256), dim3(1024), 0, stream>>>(cj1, sc1, pm1);
  local_scan1<<<dim3(256), dim3(128), 0, stream>>>(h1, sc1, pm1,
      PUl, PVl, dUl, dVl, cku1, ckv1, ckus1, ckvs1);
  prefix1_kernel<<<dim3(4), dim3(64), 0, stream>>>(cku1, ckv1, ckus1, ckvs1,
                                                   sufU1, prefV1, sufUs1, prefVs1);
  combine1_kernel<<<dim3(4096), b256, 0, stream>>>(ci1, sc1,
      sufU1, prefV1, sufUs1, prefVs1, PUl, PVl, dUl, dVl, b1, comm1e, pmn, pmx);
  quant_kernel<<<dim3(256), b256, 0, stream>>>(
      (const float4*)comm1e, comm_q2, N4, pmn, pmx, 4096, part2);
  // ---- GAT2 ----
  mfma_gemm<64, 64, false><<<dim3(4, 64), b256, 0, stream>>>(
      comm_q2, 256, W2T, 256, 256, nullptr, 0, nullptr, 0, 0, nullptr, h2b, 256);
  cicj2_kernel<<<dim3(1024), b256, 0, stream>>>(h2b, ai2, aj2, ci2, cj2);
  rank_sort_kernel<<<dim3(64), dim3(1024), 0, stream>>>(cj2, sc2, pm2);
  local_scan2<<<dim3(2, 64), b256, 0, stream>>>(h2b, sc2, pm2,
      PUl, PVl, dUl, dVl, cku2, ckv2, ckus2, ckvs2);
  prefix2_kernel<<<dim3(1), b256, 0, stream>>>(cku2, ckv2, ckus2, ckvs2,
                                               sufU2, prefV2, sufUs2, prefVs2);
  combine2_kernel<<<dim3(4096), b256, 0, stream>>>(ci2, sc2,
      sufU2, prefV2, sufUs2, prefVs2, PUl, PVl, dUl, dVl, b2, comm2_bf);
  // ---- heads (fused log-softmax + value + loss) ----
  heads_kernel<<<dim3(64), b256, 0, stream>>>(
      h_bf, comm2_bf, WaTe, bias_ext, out_logp, out_value, part1, part2, out_loss);
}